// Round 1
// baseline (3998.250 us; speedup 1.0000x reference)
//
#include <hip/hip_runtime.h>
#include <hip/hip_bf16.h>

// ---------------- problem constants ----------------
constexpr int B_   = 8;
constexpr int D_   = 512;
constexpr int L0_  = 1024;
constexpr int L_   = 1025;          // L0 + cls
constexpr int H_   = 8;
constexpr int DH_  = 64;
constexpr int DFF_ = 2048;
constexpr int NLAYER_ = 2;
constexpr int M_   = B_ * L_;       // 8200 rows
constexpr float EPS_   = 1e-6f;
constexpr float SCALE_ = 0.125f;    // 1/sqrt(64)

#define DEV_INLINE __device__ __forceinline__

DEV_INLINE float gelu_exact(float x) {
    return 0.5f * x * (1.f + erff(x * 0.70710678118654752f));
}

// ---------------- build x1/x2 ----------------
// X[(b*L + 0)*D + d] = cls[d]  for both X1, X2
__global__ __launch_bounds__(256) void write_cls_kernel(
    const float* __restrict__ cls, float* __restrict__ X1, float* __restrict__ X2) {
    int idx = blockIdx.x * 256 + threadIdx.x;      // 0 .. 8*512-1
    int b = idx >> 9;
    int d = idx & 511;
    float v = cls[d];
    X1[(size_t)b * L_ * D_ + d] = v;
    X2[(size_t)b * L_ * D_ + d] = v;
}

// embed [B, D, L0] -> X rows 1..L0 : X[(b*L + 1 + i)*D + d] = e[(b*D + d)*L0 + i]
__global__ __launch_bounds__(256) void transpose_embed_kernel(
    const float* __restrict__ e, float* __restrict__ X) {
    __shared__ float tile[32][33];
    int b  = blockIdx.z;
    int i0 = blockIdx.x * 32;       // along L0
    int d0 = blockIdx.y * 32;       // along D
    int tx = threadIdx.x;           // 0..31
    int ty = threadIdx.y;           // 0..7
#pragma unroll
    for (int j = 0; j < 32; j += 8)
        tile[ty + j][tx] = e[((size_t)b * D_ + d0 + ty + j) * L0_ + i0 + tx];
    __syncthreads();
#pragma unroll
    for (int j = 0; j < 32; j += 8)
        X[((size_t)b * L_ + 1 + i0 + ty + j) * D_ + d0 + tx] = tile[tx][ty + j];
}

// ---------------- GEMM: C[M,N] = A[M,K] * W[N,K]^T + bias[N] (opt GELU) ----------------
// BM=128, BN=64, BK=16; 256 threads; 8x4 micro-tile per thread.
template <bool GELU>
__global__ __launch_bounds__(256) void gemm_bias_kernel(
    const float* __restrict__ A, const float* __restrict__ W,
    const float* __restrict__ bias, float* __restrict__ C,
    int M, int N, int K) {
    constexpr int BM = 128, BN = 64, BK = 16;
    __shared__ float As[BK][BM];
    __shared__ float Bs[BK][BN];
    const int tid = threadIdx.x;
    const int tx = tid & 15;        // n dir: 16 threads * 4 cols = 64
    const int ty = tid >> 4;        // m dir: 16 threads * 8 rows = 128
    const int m0 = blockIdx.x * BM;
    const int n0 = blockIdx.y * BN;

    float acc[8][4];
#pragma unroll
    for (int i = 0; i < 8; ++i)
#pragma unroll
        for (int j = 0; j < 4; ++j) acc[i][j] = 0.f;

    for (int k0 = 0; k0 < K; k0 += BK) {
        // A tile: 128 rows x 16 k = 512 float4; 2 per thread
#pragma unroll
        for (int rep = 0; rep < 2; ++rep) {
            int f   = tid + rep * 256;      // 0..511
            int row = f >> 2;               // 0..127
            int kq  = f & 3;
            int gm  = m0 + row;
            float4 v = make_float4(0.f, 0.f, 0.f, 0.f);
            if (gm < M) v = *(const float4*)&A[(size_t)gm * K + k0 + kq * 4];
            As[kq * 4 + 0][row] = v.x;
            As[kq * 4 + 1][row] = v.y;
            As[kq * 4 + 2][row] = v.z;
            As[kq * 4 + 3][row] = v.w;
        }
        // W tile: 64 rows x 16 k = 256 float4; 1 per thread
        {
            int row = tid >> 2;             // 0..63
            int kq  = tid & 3;
            float4 v = *(const float4*)&W[(size_t)(n0 + row) * K + k0 + kq * 4];
            Bs[kq * 4 + 0][row] = v.x;
            Bs[kq * 4 + 1][row] = v.y;
            Bs[kq * 4 + 2][row] = v.z;
            Bs[kq * 4 + 3][row] = v.w;
        }
        __syncthreads();
#pragma unroll
        for (int kk = 0; kk < BK; ++kk) {
            float4 a0 = *(float4*)&As[kk][ty * 8];
            float4 a1 = *(float4*)&As[kk][ty * 8 + 4];
            float4 bv = *(float4*)&Bs[kk][tx * 4];
            float am[8] = {a0.x, a0.y, a0.z, a0.w, a1.x, a1.y, a1.z, a1.w};
            float bn[4] = {bv.x, bv.y, bv.z, bv.w};
#pragma unroll
            for (int i = 0; i < 8; ++i)
#pragma unroll
                for (int j = 0; j < 4; ++j)
                    acc[i][j] = fmaf(am[i], bn[j], acc[i][j]);
        }
        __syncthreads();
    }

    float4 bb = *(const float4*)&bias[n0 + tx * 4];
#pragma unroll
    for (int i = 0; i < 8; ++i) {
        int gm = m0 + ty * 8 + i;
        if (gm < M) {
            float4 o;
            o.x = acc[i][0] + bb.x;
            o.y = acc[i][1] + bb.y;
            o.z = acc[i][2] + bb.z;
            o.w = acc[i][3] + bb.w;
            if (GELU) {
                o.x = gelu_exact(o.x); o.y = gelu_exact(o.y);
                o.z = gelu_exact(o.z); o.w = gelu_exact(o.w);
            }
            *(float4*)&C[(size_t)gm * N + n0 + tx * 4] = o;
        }
    }
}

// ---------------- flash attention (fp32) ----------------
// grid (qt, h, b), block 128. 1 thread = 1 q row. K/V tiles of 16 rows in LDS.
__global__ __launch_bounds__(128) void attn_kernel(
    const float* __restrict__ Q, const float* __restrict__ Kb,
    const float* __restrict__ Vb, float* __restrict__ O) {
    constexpr int KT = 16;
    __shared__ float Kl[KT][DH_];
    __shared__ float Vl[KT][DH_];
    const int tid = threadIdx.x;
    const int qt = blockIdx.x, h = blockIdx.y, b = blockIdx.z;
    const int r = qt * 128 + tid;
    const bool active = r < L_;
    const int col0 = h * DH_;
    const size_t qbase = ((size_t)b * L_ + (active ? r : 0)) * D_ + col0;

    float q[DH_];
#pragma unroll
    for (int d4 = 0; d4 < 16; ++d4) {
        float4 v = *(const float4*)&Q[qbase + d4 * 4];
        if (!active) v = make_float4(0.f, 0.f, 0.f, 0.f);
        q[d4 * 4 + 0] = v.x; q[d4 * 4 + 1] = v.y;
        q[d4 * 4 + 2] = v.z; q[d4 * 4 + 3] = v.w;
    }
    float o[DH_];
#pragma unroll
    for (int d = 0; d < DH_; ++d) o[d] = 0.f;
    float mrun = -1e30f, lrun = 0.f;

    for (int kt = 0; kt < L_; kt += KT) {
        // stage KT rows of K and V (16 rows * 16 float4 = 256 f4; 2 per thread)
#pragma unroll
        for (int i = 0; i < 2; ++i) {
            int f   = tid + i * 128;      // 0..255
            int row = f >> 4;             // 0..15
            int cq  = f & 15;
            int kr  = kt + row;
            size_t gb = ((size_t)b * L_ + (kr < L_ ? kr : 0)) * D_ + col0 + cq * 4;
            float4 kv = *(const float4*)&Kb[gb];
            float4 vv = *(const float4*)&Vb[gb];
            if (kr >= L_) { kv = make_float4(0.f,0.f,0.f,0.f); vv = kv; }
            *(float4*)&Kl[row][cq * 4] = kv;
            *(float4*)&Vl[row][cq * 4] = vv;
        }
        __syncthreads();

        float p[KT];
#pragma unroll
        for (int j = 0; j < KT; ++j) {
            float s = 0.f;
#pragma unroll
            for (int d4 = 0; d4 < 16; ++d4) {
                float4 kv = *(float4*)&Kl[j][d4 * 4];
                s = fmaf(q[d4 * 4 + 0], kv.x, s);
                s = fmaf(q[d4 * 4 + 1], kv.y, s);
                s = fmaf(q[d4 * 4 + 2], kv.z, s);
                s = fmaf(q[d4 * 4 + 3], kv.w, s);
            }
            p[j] = (kt + j < L_) ? s * SCALE_ : -1e30f;
        }
        float mt = mrun;
#pragma unroll
        for (int j = 0; j < KT; ++j) mt = fmaxf(mt, p[j]);
        float scl = __expf(mrun - mt);
        float ls = 0.f;
#pragma unroll
        for (int j = 0; j < KT; ++j) { p[j] = __expf(p[j] - mt); ls += p[j]; }
        mrun = mt;
        lrun = lrun * scl + ls;
#pragma unroll
        for (int d4 = 0; d4 < 16; ++d4) {
            float4 a;
            a.x = o[d4 * 4 + 0] * scl; a.y = o[d4 * 4 + 1] * scl;
            a.z = o[d4 * 4 + 2] * scl; a.w = o[d4 * 4 + 3] * scl;
#pragma unroll
            for (int j = 0; j < KT; ++j) {
                float4 vv = *(float4*)&Vl[j][d4 * 4];
                a.x = fmaf(p[j], vv.x, a.x);
                a.y = fmaf(p[j], vv.y, a.y);
                a.z = fmaf(p[j], vv.z, a.z);
                a.w = fmaf(p[j], vv.w, a.w);
            }
            o[d4 * 4 + 0] = a.x; o[d4 * 4 + 1] = a.y;
            o[d4 * 4 + 2] = a.z; o[d4 * 4 + 3] = a.w;
        }
        __syncthreads();
    }

    if (active) {
        float inv = 1.f / lrun;
#pragma unroll
        for (int d4 = 0; d4 < 16; ++d4) {
            float4 v;
            v.x = o[d4 * 4 + 0] * inv; v.y = o[d4 * 4 + 1] * inv;
            v.z = o[d4 * 4 + 2] * inv; v.w = o[d4 * 4 + 3] * inv;
            *(float4*)&O[qbase + d4 * 4] = v;
        }
    }
}

// ---------------- fused residual add + LayerNorm ----------------
// Out[row] = LN(X[row] + Y[row]) * g + b ; one wave per row, 4 rows per block.
__global__ __launch_bounds__(256) void add_ln_kernel(
    const float* __restrict__ X, const float* __restrict__ Y,
    const float* __restrict__ g, const float* __restrict__ be,
    float* __restrict__ Out) {
    int wave = threadIdx.x >> 6;
    int lane = threadIdx.x & 63;
    int row = blockIdx.x * 4 + wave;
    if (row >= M_) return;
    size_t base = (size_t)row * D_;
    int c0 = lane * 4, c1 = 256 + lane * 4;
    float4 xa = *(const float4*)&X[base + c0];
    float4 xb = *(const float4*)&X[base + c1];
    float4 ya = *(const float4*)&Y[base + c0];
    float4 yb = *(const float4*)&Y[base + c1];
    float v[8] = {xa.x + ya.x, xa.y + ya.y, xa.z + ya.z, xa.w + ya.w,
                  xb.x + yb.x, xb.y + yb.y, xb.z + yb.z, xb.w + yb.w};
    float s = 0.f, s2 = 0.f;
#pragma unroll
    for (int i = 0; i < 8; ++i) { s += v[i]; s2 = fmaf(v[i], v[i], s2); }
#pragma unroll
    for (int off = 32; off > 0; off >>= 1) {
        s  += __shfl_xor(s, off);
        s2 += __shfl_xor(s2, off);
    }
    float mean = s * (1.f / D_);
    float var  = s2 * (1.f / D_) - mean * mean;
    float rstd = rsqrtf(var + EPS_);
    float4 ga = *(const float4*)&g[c0];
    float4 gb = *(const float4*)&g[c1];
    float4 ba = *(const float4*)&be[c0];
    float4 bb = *(const float4*)&be[c1];
    float4 oa, ob;
    oa.x = (v[0] - mean) * rstd * ga.x + ba.x;
    oa.y = (v[1] - mean) * rstd * ga.y + ba.y;
    oa.z = (v[2] - mean) * rstd * ga.z + ba.z;
    oa.w = (v[3] - mean) * rstd * ga.w + ba.w;
    ob.x = (v[4] - mean) * rstd * gb.x + bb.x;
    ob.y = (v[5] - mean) * rstd * gb.y + bb.y;
    ob.z = (v[6] - mean) * rstd * gb.z + bb.z;
    ob.w = (v[7] - mean) * rstd * gb.w + bb.w;
    *(float4*)&Out[base + c0] = oa;
    *(float4*)&Out[base + c1] = ob;
}

// ---------------- launch ----------------
extern "C" void kernel_launch(void* const* d_in, const int* in_sizes, int n_in,
                              void* d_out, int out_size, void* d_ws, size_t ws_size,
                              hipStream_t stream) {
    const float* embed1 = (const float*)d_in[0];
    const float* embed2 = (const float*)d_in[1];
    const float* cls    = (const float*)d_in[2];
    const float* Wq = (const float*)d_in[3];
    const float* bq = (const float*)d_in[4];
    const float* Wk = (const float*)d_in[5];
    const float* bk = (const float*)d_in[6];
    const float* Wv = (const float*)d_in[7];
    const float* bv = (const float*)d_in[8];
    const float* Wo = (const float*)d_in[9];
    const float* bo = (const float*)d_in[10];
    const float* ln1g = (const float*)d_in[11];
    const float* ln1b = (const float*)d_in[12];
    const float* W1 = (const float*)d_in[13];
    const float* b1 = (const float*)d_in[14];
    const float* W2 = (const float*)d_in[15];
    const float* b2 = (const float*)d_in[16];
    const float* ln2g = (const float*)d_in[17];
    const float* ln2b = (const float*)d_in[18];

    const size_t SZ = (size_t)M_ * D_;      // 4,198,400 floats
    float* ws = (float*)d_ws;
    float* X  = ws;                          // running stream / x1
    float* X2 = ws + SZ;                     // x2 (constant across layers)
    float* Qb = ws + 2 * SZ;
    float* Kb = ws + 3 * SZ;
    float* Vb = ws + 4 * SZ;
    float* Tb = ws + 5 * SZ;
    float* Hb = ws + 6 * SZ;                 // [M, DFF]

    // build x1 / x2
    write_cls_kernel<<<(B_ * D_) / 256, 256, 0, stream>>>(cls, X, X2);
    transpose_embed_kernel<<<dim3(L0_ / 32, D_ / 32, B_), dim3(32, 8), 0, stream>>>(embed1, X);
    transpose_embed_kernel<<<dim3(L0_ / 32, D_ / 32, B_), dim3(32, 8), 0, stream>>>(embed2, X2);

    const int GM = (M_ + 127) / 128;         // 65
    dim3 gemm_blk(256);

    for (int l = 0; l < NLAYER_; ++l) {
        const float* Wq_l = Wq + (size_t)l * D_ * D_;
        const float* Wk_l = Wk + (size_t)l * D_ * D_;
        const float* Wv_l = Wv + (size_t)l * D_ * D_;
        const float* Wo_l = Wo + (size_t)l * D_ * D_;
        const float* W1_l = W1 + (size_t)l * DFF_ * D_;
        const float* W2_l = W2 + (size_t)l * D_ * DFF_;

        gemm_bias_kernel<false><<<dim3(GM, D_ / 64), gemm_blk, 0, stream>>>(
            X, Wq_l, bq + l * D_, Qb, M_, D_, D_);
        gemm_bias_kernel<false><<<dim3(GM, D_ / 64), gemm_blk, 0, stream>>>(
            X2, Wk_l, bk + l * D_, Kb, M_, D_, D_);
        gemm_bias_kernel<false><<<dim3(GM, D_ / 64), gemm_blk, 0, stream>>>(
            X2, Wv_l, bv + l * D_, Vb, M_, D_, D_);

        attn_kernel<<<dim3((L_ + 127) / 128, H_, B_), 128, 0, stream>>>(Qb, Kb, Vb, Tb);

        gemm_bias_kernel<false><<<dim3(GM, D_ / 64), gemm_blk, 0, stream>>>(
            Tb, Wo_l, bo + l * D_, Qb, M_, D_, D_);

        add_ln_kernel<<<(M_ + 3) / 4, 256, 0, stream>>>(
            X, Qb, ln1g + l * D_, ln1b + l * D_, X);

        gemm_bias_kernel<true><<<dim3(GM, DFF_ / 64), gemm_blk, 0, stream>>>(
            X, W1_l, b1 + l * DFF_, Hb, M_, DFF_, D_);
        gemm_bias_kernel<false><<<dim3(GM, D_ / 64), gemm_blk, 0, stream>>>(
            Hb, W2_l, b2 + l * D_, Tb, M_, D_, DFF_);

        float* out_ptr = (l == NLAYER_ - 1) ? (float*)d_out : X;
        add_ln_kernel<<<(M_ + 3) / 4, 256, 0, stream>>>(
            X, Tb, ln2g + l * D_, ln2b + l * D_, out_ptr);
    }
}

// Round 2
// 3017.225 us; speedup vs baseline: 1.3251x; 1.3251x over previous
//
#include <hip/hip_runtime.h>
#include <hip/hip_bf16.h>

// ---------------- problem constants ----------------
constexpr int B_   = 8;
constexpr int D_   = 512;
constexpr int L0_  = 1024;
constexpr int L_   = 1025;          // L0 + cls
constexpr int H_   = 8;
constexpr int DH_  = 64;
constexpr int DFF_ = 2048;
constexpr int NLAYER_ = 2;
constexpr int M_   = B_ * L_;       // 8200 rows
constexpr float EPS_   = 1e-6f;
constexpr float SCALE_ = 0.125f;    // 1/sqrt(64)

#define DEV_INLINE __device__ __forceinline__

DEV_INLINE float gelu_exact(float x) {
    return 0.5f * x * (1.f + erff(x * 0.70710678118654752f));
}

// ---------------- build x1/x2 ----------------
__global__ __launch_bounds__(256) void write_cls_kernel(
    const float* __restrict__ cls, float* __restrict__ X1, float* __restrict__ X2) {
    int idx = blockIdx.x * 256 + threadIdx.x;      // 0 .. 8*512-1
    int b = idx >> 9;
    int d = idx & 511;
    float v = cls[d];
    X1[(size_t)b * L_ * D_ + d] = v;
    X2[(size_t)b * L_ * D_ + d] = v;
}

// embed [B, D, L0] -> X rows 1..L0
__global__ __launch_bounds__(256) void transpose_embed_kernel(
    const float* __restrict__ e, float* __restrict__ X) {
    __shared__ float tile[32][33];
    int b  = blockIdx.z;
    int i0 = blockIdx.x * 32;       // along L0
    int d0 = blockIdx.y * 32;       // along D
    int tx = threadIdx.x;           // 0..31
    int ty = threadIdx.y;           // 0..7
#pragma unroll
    for (int j = 0; j < 32; j += 8)
        tile[ty + j][tx] = e[((size_t)b * D_ + d0 + ty + j) * L0_ + i0 + tx];
    __syncthreads();
#pragma unroll
    for (int j = 0; j < 32; j += 8)
        X[((size_t)b * L_ + 1 + i0 + ty + j) * D_ + d0 + tx] = tile[tx][ty + j];
}

// ---------------- GEMM: C[M,N] = A[M,K] * W[N,K]^T + bias[N] (opt GELU) ----------------
template <bool GELU>
__global__ __launch_bounds__(256) void gemm_bias_kernel(
    const float* __restrict__ A, const float* __restrict__ W,
    const float* __restrict__ bias, float* __restrict__ C,
    int M, int N, int K) {
    constexpr int BM = 128, BN = 64, BK = 16;
    __shared__ float As[BK][BM];
    __shared__ float Bs[BK][BN];
    const int tid = threadIdx.x;
    const int tx = tid & 15;
    const int ty = tid >> 4;
    const int m0 = blockIdx.x * BM;
    const int n0 = blockIdx.y * BN;

    float acc[8][4];
#pragma unroll
    for (int i = 0; i < 8; ++i)
#pragma unroll
        for (int j = 0; j < 4; ++j) acc[i][j] = 0.f;

    for (int k0 = 0; k0 < K; k0 += BK) {
#pragma unroll
        for (int rep = 0; rep < 2; ++rep) {
            int f   = tid + rep * 256;
            int row = f >> 2;
            int kq  = f & 3;
            int gm  = m0 + row;
            float4 v = make_float4(0.f, 0.f, 0.f, 0.f);
            if (gm < M) v = *(const float4*)&A[(size_t)gm * K + k0 + kq * 4];
            As[kq * 4 + 0][row] = v.x;
            As[kq * 4 + 1][row] = v.y;
            As[kq * 4 + 2][row] = v.z;
            As[kq * 4 + 3][row] = v.w;
        }
        {
            int row = tid >> 2;
            int kq  = tid & 3;
            float4 v = *(const float4*)&W[(size_t)(n0 + row) * K + k0 + kq * 4];
            Bs[kq * 4 + 0][row] = v.x;
            Bs[kq * 4 + 1][row] = v.y;
            Bs[kq * 4 + 2][row] = v.z;
            Bs[kq * 4 + 3][row] = v.w;
        }
        __syncthreads();
#pragma unroll
        for (int kk = 0; kk < BK; ++kk) {
            float4 a0 = *(float4*)&As[kk][ty * 8];
            float4 a1 = *(float4*)&As[kk][ty * 8 + 4];
            float4 bv = *(float4*)&Bs[kk][tx * 4];
            float am[8] = {a0.x, a0.y, a0.z, a0.w, a1.x, a1.y, a1.z, a1.w};
            float bn[4] = {bv.x, bv.y, bv.z, bv.w};
#pragma unroll
            for (int i = 0; i < 8; ++i)
#pragma unroll
                for (int j = 0; j < 4; ++j)
                    acc[i][j] = fmaf(am[i], bn[j], acc[i][j]);
        }
        __syncthreads();
    }

    float4 bb = *(const float4*)&bias[n0 + tx * 4];
#pragma unroll
    for (int i = 0; i < 8; ++i) {
        int gm = m0 + ty * 8 + i;
        if (gm < M) {
            float4 o;
            o.x = acc[i][0] + bb.x;
            o.y = acc[i][1] + bb.y;
            o.z = acc[i][2] + bb.z;
            o.w = acc[i][3] + bb.w;
            if (GELU) {
                o.x = gelu_exact(o.x); o.y = gelu_exact(o.y);
                o.z = gelu_exact(o.z); o.w = gelu_exact(o.w);
            }
            *(float4*)&C[(size_t)gm * N + n0 + tx * 4] = o;
        }
    }
}

// ---------------- flash attention (fp32), 4 lanes per q-row ----------------
// block = 256 threads = 4 waves; each wave: 16 q-rows x 4 dh-slices.
// grid (ceil(L/64), H, B). KT=32 key rows staged in LDS (padded).
__global__ __launch_bounds__(256) void attn_kernel(
    const float* __restrict__ Q, const float* __restrict__ Kb,
    const float* __restrict__ Vb, float* __restrict__ O) {
    constexpr int KT = 32;
    constexpr int QT = 64;
    constexpr int LDP = 68;                 // padded row stride (floats)
    __shared__ float Kl[KT][LDP];
    __shared__ float Vl[KT][LDP];
    const int tid  = threadIdx.x;
    const int lane = tid & 63;
    const int wave = tid >> 6;
    const int s    = lane >> 4;             // dh slice 0..3 (16 floats)
    const int r_loc = wave * 16 + (lane & 15);
    const int qt = blockIdx.x, h = blockIdx.y, b = blockIdx.z;
    const int row  = qt * QT + r_loc;
    const bool active = row < L_;
    const int rowc = active ? row : (L_ - 1);
    const int col0 = h * DH_;
    const size_t qbase = ((size_t)b * L_ + rowc) * D_ + col0 + s * 16;

    float q[16];
#pragma unroll
    for (int i = 0; i < 4; ++i) {
        float4 v = *(const float4*)&Q[qbase + i * 4];
        q[4*i+0] = v.x; q[4*i+1] = v.y; q[4*i+2] = v.z; q[4*i+3] = v.w;
    }
    float o[16];
#pragma unroll
    for (int i = 0; i < 16; ++i) o[i] = 0.f;
    float m = -1e30f, l = 0.f;

    for (int kt = 0; kt < L_; kt += KT) {
        // stage K,V tile: 32 rows x 16 float4 each; 2 f4/thread/matrix
#pragma unroll
        for (int rep = 0; rep < 2; ++rep) {
            int f  = tid + rep * 256;       // 0..511
            int kr = f >> 4;                // 0..31
            int cq = f & 15;
            int g  = kt + kr;
            size_t gb = ((size_t)b * L_ + (g < L_ ? g : L_ - 1)) * D_ + col0 + cq * 4;
            *(float4*)&Kl[kr][cq * 4] = *(const float4*)&Kb[gb];
            *(float4*)&Vl[kr][cq * 4] = *(const float4*)&Vb[gb];
        }
        __syncthreads();

        float p[KT];
#pragma unroll
        for (int j = 0; j < KT; ++j) {
            float4 k0 = *(float4*)&Kl[j][s * 16 + 0];
            float4 k1 = *(float4*)&Kl[j][s * 16 + 4];
            float4 k2 = *(float4*)&Kl[j][s * 16 + 8];
            float4 k3 = *(float4*)&Kl[j][s * 16 + 12];
            float t = 0.f;
            t = fmaf(q[0],  k0.x, t); t = fmaf(q[1],  k0.y, t);
            t = fmaf(q[2],  k0.z, t); t = fmaf(q[3],  k0.w, t);
            t = fmaf(q[4],  k1.x, t); t = fmaf(q[5],  k1.y, t);
            t = fmaf(q[6],  k1.z, t); t = fmaf(q[7],  k1.w, t);
            t = fmaf(q[8],  k2.x, t); t = fmaf(q[9],  k2.y, t);
            t = fmaf(q[10], k2.z, t); t = fmaf(q[11], k2.w, t);
            t = fmaf(q[12], k3.x, t); t = fmaf(q[13], k3.y, t);
            t = fmaf(q[14], k3.z, t); t = fmaf(q[15], k3.w, t);
            p[j] = t;
        }
        // combine the 4 dh-slices (lanes differ in bits 4,5 of lane id)
#pragma unroll
        for (int j = 0; j < KT; ++j) {
            float t = p[j];
            t += __shfl_xor(t, 16);
            t += __shfl_xor(t, 32);
            p[j] = (kt + j < L_) ? t * SCALE_ : -1e30f;
        }
        float mt = m;
#pragma unroll
        for (int j = 0; j < KT; ++j) mt = fmaxf(mt, p[j]);
        float scl = __expf(m - mt);
        float ls = 0.f;
#pragma unroll
        for (int j = 0; j < KT; ++j) { p[j] = __expf(p[j] - mt); ls += p[j]; }
        m = mt;
        l = l * scl + ls;
#pragma unroll
        for (int i = 0; i < 16; ++i) o[i] *= scl;
#pragma unroll
        for (int j = 0; j < KT; ++j) {
            float4 v0 = *(float4*)&Vl[j][s * 16 + 0];
            float4 v1 = *(float4*)&Vl[j][s * 16 + 4];
            float4 v2 = *(float4*)&Vl[j][s * 16 + 8];
            float4 v3 = *(float4*)&Vl[j][s * 16 + 12];
            float pj = p[j];
            o[0]  = fmaf(pj, v0.x, o[0]);  o[1]  = fmaf(pj, v0.y, o[1]);
            o[2]  = fmaf(pj, v0.z, o[2]);  o[3]  = fmaf(pj, v0.w, o[3]);
            o[4]  = fmaf(pj, v1.x, o[4]);  o[5]  = fmaf(pj, v1.y, o[5]);
            o[6]  = fmaf(pj, v1.z, o[6]);  o[7]  = fmaf(pj, v1.w, o[7]);
            o[8]  = fmaf(pj, v2.x, o[8]);  o[9]  = fmaf(pj, v2.y, o[9]);
            o[10] = fmaf(pj, v2.z, o[10]); o[11] = fmaf(pj, v2.w, o[11]);
            o[12] = fmaf(pj, v3.x, o[12]); o[13] = fmaf(pj, v3.y, o[13]);
            o[14] = fmaf(pj, v3.z, o[14]); o[15] = fmaf(pj, v3.w, o[15]);
        }
        __syncthreads();
    }

    if (active) {
        float inv = 1.f / l;
#pragma unroll
        for (int i = 0; i < 4; ++i) {
            float4 v;
            v.x = o[4*i+0] * inv; v.y = o[4*i+1] * inv;
            v.z = o[4*i+2] * inv; v.w = o[4*i+3] * inv;
            *(float4*)&O[qbase + i * 4] = v;
        }
    }
}

// ---------------- fused residual add + LayerNorm ----------------
__global__ __launch_bounds__(256) void add_ln_kernel(
    const float* __restrict__ X, const float* __restrict__ Y,
    const float* __restrict__ g, const float* __restrict__ be,
    float* __restrict__ Out) {
    int wave = threadIdx.x >> 6;
    int lane = threadIdx.x & 63;
    int row = blockIdx.x * 4 + wave;
    if (row >= M_) return;
    size_t base = (size_t)row * D_;
    int c0 = lane * 4, c1 = 256 + lane * 4;
    float4 xa = *(const float4*)&X[base + c0];
    float4 xb = *(const float4*)&X[base + c1];
    float4 ya = *(const float4*)&Y[base + c0];
    float4 yb = *(const float4*)&Y[base + c1];
    float v[8] = {xa.x + ya.x, xa.y + ya.y, xa.z + ya.z, xa.w + ya.w,
                  xb.x + yb.x, xb.y + yb.y, xb.z + yb.z, xb.w + yb.w};
    float s = 0.f, s2 = 0.f;
#pragma unroll
    for (int i = 0; i < 8; ++i) { s += v[i]; s2 = fmaf(v[i], v[i], s2); }
#pragma unroll
    for (int off = 32; off > 0; off >>= 1) {
        s  += __shfl_xor(s, off);
        s2 += __shfl_xor(s2, off);
    }
    float mean = s * (1.f / D_);
    float var  = s2 * (1.f / D_) - mean * mean;
    float rstd = rsqrtf(var + EPS_);
    float4 ga = *(const float4*)&g[c0];
    float4 gb = *(const float4*)&g[c1];
    float4 ba = *(const float4*)&be[c0];
    float4 bb = *(const float4*)&be[c1];
    float4 oa, ob;
    oa.x = (v[0] - mean) * rstd * ga.x + ba.x;
    oa.y = (v[1] - mean) * rstd * ga.y + ba.y;
    oa.z = (v[2] - mean) * rstd * ga.z + ba.z;
    oa.w = (v[3] - mean) * rstd * ga.w + ba.w;
    ob.x = (v[4] - mean) * rstd * gb.x + bb.x;
    ob.y = (v[5] - mean) * rstd * gb.y + bb.y;
    ob.z = (v[6] - mean) * rstd * gb.z + bb.z;
    ob.w = (v[7] - mean) * rstd * gb.w + bb.w;
    *(float4*)&Out[base + c0] = oa;
    *(float4*)&Out[base + c1] = ob;
}

// ---------------- launch ----------------
extern "C" void kernel_launch(void* const* d_in, const int* in_sizes, int n_in,
                              void* d_out, int out_size, void* d_ws, size_t ws_size,
                              hipStream_t stream) {
    const float* embed1 = (const float*)d_in[0];
    const float* embed2 = (const float*)d_in[1];
    const float* cls    = (const float*)d_in[2];
    const float* Wq = (const float*)d_in[3];
    const float* bq = (const float*)d_in[4];
    const float* Wk = (const float*)d_in[5];
    const float* bk = (const float*)d_in[6];
    const float* Wv = (const float*)d_in[7];
    const float* bv = (const float*)d_in[8];
    const float* Wo = (const float*)d_in[9];
    const float* bo = (const float*)d_in[10];
    const float* ln1g = (const float*)d_in[11];
    const float* ln1b = (const float*)d_in[12];
    const float* W1 = (const float*)d_in[13];
    const float* b1 = (const float*)d_in[14];
    const float* W2 = (const float*)d_in[15];
    const float* b2 = (const float*)d_in[16];
    const float* ln2g = (const float*)d_in[17];
    const float* ln2b = (const float*)d_in[18];

    const size_t SZ = (size_t)M_ * D_;
    float* ws = (float*)d_ws;
    float* X  = ws;
    float* X2 = ws + SZ;
    float* Qb = ws + 2 * SZ;
    float* Kb = ws + 3 * SZ;
    float* Vb = ws + 4 * SZ;
    float* Tb = ws + 5 * SZ;
    float* Hb = ws + 6 * SZ;                 // [M, DFF]

    write_cls_kernel<<<(B_ * D_) / 256, 256, 0, stream>>>(cls, X, X2);
    transpose_embed_kernel<<<dim3(L0_ / 32, D_ / 32, B_), dim3(32, 8), 0, stream>>>(embed1, X);
    transpose_embed_kernel<<<dim3(L0_ / 32, D_ / 32, B_), dim3(32, 8), 0, stream>>>(embed2, X2);

    const int GM = (M_ + 127) / 128;         // 65
    dim3 gemm_blk(256);

    for (int l = 0; l < NLAYER_; ++l) {
        const float* Wq_l = Wq + (size_t)l * D_ * D_;
        const float* Wk_l = Wk + (size_t)l * D_ * D_;
        const float* Wv_l = Wv + (size_t)l * D_ * D_;
        const float* Wo_l = Wo + (size_t)l * D_ * D_;
        const float* W1_l = W1 + (size_t)l * DFF_ * D_;
        const float* W2_l = W2 + (size_t)l * D_ * DFF_;

        gemm_bias_kernel<false><<<dim3(GM, D_ / 64), gemm_blk, 0, stream>>>(
            X, Wq_l, bq + l * D_, Qb, M_, D_, D_);
        gemm_bias_kernel<false><<<dim3(GM, D_ / 64), gemm_blk, 0, stream>>>(
            X2, Wk_l, bk + l * D_, Kb, M_, D_, D_);
        gemm_bias_kernel<false><<<dim3(GM, D_ / 64), gemm_blk, 0, stream>>>(
            X2, Wv_l, bv + l * D_, Vb, M_, D_, D_);

        attn_kernel<<<dim3((L_ + 63) / 64, H_, B_), 256, 0, stream>>>(Qb, Kb, Vb, Tb);

        gemm_bias_kernel<false><<<dim3(GM, D_ / 64), gemm_blk, 0, stream>>>(
            Tb, Wo_l, bo + l * D_, Qb, M_, D_, D_);

        add_ln_kernel<<<(M_ + 3) / 4, 256, 0, stream>>>(
            X, Qb, ln1g + l * D_, ln1b + l * D_, X);

        gemm_bias_kernel<true><<<dim3(GM, DFF_ / 64), gemm_blk, 0, stream>>>(
            X, W1_l, b1 + l * DFF_, Hb, M_, DFF_, D_);
        gemm_bias_kernel<false><<<dim3(GM, D_ / 64), gemm_blk, 0, stream>>>(
            Hb, W2_l, b2 + l * D_, Tb, M_, D_, DFF_);

        float* out_ptr = (l == NLAYER_ - 1) ? (float*)d_out : X;
        add_ln_kernel<<<(M_ + 3) / 4, 256, 0, stream>>>(
            X, Tb, ln2g + l * D_, ln2b + l * D_, out_ptr);
    }
}

// Round 4
// 1774.338 us; speedup vs baseline: 2.2534x; 1.7005x over previous
//
#include <hip/hip_runtime.h>
#include <hip/hip_bf16.h>

// ---------------- problem constants ----------------
constexpr int B_   = 8;
constexpr int D_   = 512;
constexpr int L0_  = 1024;
constexpr int L_   = 1025;          // L0 + cls
constexpr int H_   = 8;
constexpr int DH_  = 64;
constexpr int DFF_ = 2048;
constexpr int NLAYER_ = 2;
constexpr int M_   = B_ * L_;       // 8200 rows
constexpr float EPS_   = 1e-6f;
constexpr float SCALE_ = 0.125f;    // 1/sqrt(64)

#define DEV_INLINE __device__ __forceinline__

typedef __attribute__((ext_vector_type(8))) __bf16 bf16x8;
typedef __attribute__((ext_vector_type(4))) __bf16 bf16x4;
typedef __attribute__((ext_vector_type(4))) float  f32x4;

DEV_INLINE float gelu_exact(float x) {
    return 0.5f * x * (1.f + erff(x * 0.70710678118654752f));
}

struct bfpair { __bf16 h, l; };
// split fp32 into bf16 hi + bf16 lo (v ≈ h + l, residual ~2^-18 |v|)
DEV_INLINE bfpair split_bf(float v) {
    bfpair p;
    p.h = (__bf16)v;
    p.l = (__bf16)(v - (float)p.h);
    return p;
}

// ---------------- build x1/x2 ----------------
__global__ __launch_bounds__(256) void write_cls_kernel(
    const float* __restrict__ cls, float* __restrict__ X1, float* __restrict__ X2) {
    int idx = blockIdx.x * 256 + threadIdx.x;      // 0 .. 8*512-1
    int b = idx >> 9;
    int d = idx & 511;
    float v = cls[d];
    X1[(size_t)b * L_ * D_ + d] = v;
    X2[(size_t)b * L_ * D_ + d] = v;
}

// embed [B, D, L0] -> X rows 1..L0
__global__ __launch_bounds__(256) void transpose_embed_kernel(
    const float* __restrict__ e, float* __restrict__ X) {
    __shared__ float tile[32][33];
    int b  = blockIdx.z;
    int i0 = blockIdx.x * 32;       // along L0
    int d0 = blockIdx.y * 32;       // along D
    int tx = threadIdx.x;           // 0..31
    int ty = threadIdx.y;           // 0..7
#pragma unroll
    for (int j = 0; j < 32; j += 8)
        tile[ty + j][tx] = e[((size_t)b * D_ + d0 + ty + j) * L0_ + i0 + tx];
    __syncthreads();
#pragma unroll
    for (int j = 0; j < 32; j += 8)
        X[((size_t)b * L_ + 1 + i0 + ty + j) * D_ + d0 + tx] = tile[tx][ty + j];
}

// ---------------- split-bf16 MFMA GEMM ----------------
// C[M,N] = A[M,K] * W[N,K]^T + bias[N], fp32 in/out, internally 3-pass
// split-bf16 (hi*hi + hi*lo + lo*hi) via v_mfma_f32_16x16x32_bf16.
// BM=128 BN=64 BK=32; 256 threads = 4 waves, each wave owns 64x32 (4x2 frags).
template <bool GELU>
__global__ __launch_bounds__(256) void gemm_mfma_kernel(
    const float* __restrict__ A, const float* __restrict__ W,
    const float* __restrict__ bias, float* __restrict__ C,
    int M, int N, int K) {
    constexpr int BM = 128, BN = 64, BK = 32;
    constexpr int LDK = BK + 8;   // 40 bf16 = 80B row stride (bank-friendly)
    __shared__ alignas(16) __bf16 Ahs[BM][LDK];
    __shared__ alignas(16) __bf16 Als[BM][LDK];
    __shared__ alignas(16) __bf16 Bhs[BN][LDK];
    __shared__ alignas(16) __bf16 Bls[BN][LDK];

    const int GM = (M + BM - 1) / BM;
    // bijective XCD swizzle over the flat grid
    const int nwg = gridDim.x;
    int bid = blockIdx.x;
    {
        int q = nwg >> 3, r = nwg & 7;
        int xcd = bid & 7, pos = bid >> 3;
        bid = (xcd < r) ? xcd * (q + 1) + pos
                        : r * (q + 1) + (xcd - r) * q + pos;
    }
    const int bn = bid / GM;
    const int bm = bid % GM;
    const int m0 = bm * BM;
    const int n0 = bn * BN;

    const int tid  = threadIdx.x;
    const int lane = tid & 63;
    const int wv   = tid >> 6;
    const int wr   = wv >> 1;          // 0..1 (m half)
    const int wc   = wv & 1;           // 0..1 (n half)
    const int fr   = lane & 15;
    const int fq   = lane >> 4;        // 0..3
    const int fq8  = fq * 8;
    const int mb   = wr * 64;
    const int nb   = wc * 32;

    // staging geometry: thread -> (row = tid>>3 + rep*32, q = tid&7)
    const int srow = tid >> 3;
    const int sq   = tid & 7;
    size_t aOff[4], wOff[2];
#pragma unroll
    for (int rep = 0; rep < 4; ++rep) {
        int r = m0 + srow + rep * 32;
        if (r > M - 1) r = M - 1;
        aOff[rep] = (size_t)r * K + sq * 4;
    }
#pragma unroll
    for (int rep = 0; rep < 2; ++rep)
        wOff[rep] = (size_t)(n0 + srow + rep * 32) * K + sq * 4;

    f32x4 acc[4][2];
#pragma unroll
    for (int i = 0; i < 4; ++i)
#pragma unroll
        for (int j = 0; j < 2; ++j) acc[i][j] = (f32x4){0.f, 0.f, 0.f, 0.f};

    const int nk = K / BK;
    float4 aR[4], wR[2];
#pragma unroll
    for (int rep = 0; rep < 4; ++rep) aR[rep] = *(const float4*)&A[aOff[rep]];
#pragma unroll
    for (int rep = 0; rep < 2; ++rep) wR[rep] = *(const float4*)&W[wOff[rep]];

    for (int kt = 0; kt < nk; ++kt) {
        // ---- stage regs -> LDS (split hi/lo) ----
#pragma unroll
        for (int rep = 0; rep < 4; ++rep) {
            int row = srow + rep * 32;
            bf16x4 h, l;
            bfpair p0 = split_bf(aR[rep].x); h[0] = p0.h; l[0] = p0.l;
            bfpair p1 = split_bf(aR[rep].y); h[1] = p1.h; l[1] = p1.l;
            bfpair p2 = split_bf(aR[rep].z); h[2] = p2.h; l[2] = p2.l;
            bfpair p3 = split_bf(aR[rep].w); h[3] = p3.h; l[3] = p3.l;
            *(bf16x4*)&Ahs[row][sq * 4] = h;
            *(bf16x4*)&Als[row][sq * 4] = l;
        }
#pragma unroll
        for (int rep = 0; rep < 2; ++rep) {
            int row = srow + rep * 32;
            bf16x4 h, l;
            bfpair p0 = split_bf(wR[rep].x); h[0] = p0.h; l[0] = p0.l;
            bfpair p1 = split_bf(wR[rep].y); h[1] = p1.h; l[1] = p1.l;
            bfpair p2 = split_bf(wR[rep].z); h[2] = p2.h; l[2] = p2.l;
            bfpair p3 = split_bf(wR[rep].w); h[3] = p3.h; l[3] = p3.l;
            *(bf16x4*)&Bhs[row][sq * 4] = h;
            *(bf16x4*)&Bls[row][sq * 4] = l;
        }
        __syncthreads();

        // ---- issue next-tile global loads (latency hides under MFMA) ----
        if (kt + 1 < nk) {
            int k0 = (kt + 1) * BK;
#pragma unroll
            for (int rep = 0; rep < 4; ++rep) aR[rep] = *(const float4*)&A[aOff[rep] + k0];
#pragma unroll
            for (int rep = 0; rep < 2; ++rep) wR[rep] = *(const float4*)&W[wOff[rep] + k0];
        }

        // ---- fragments ----
        bf16x8 ah[4], al[4], bh[2], bl[2];
#pragma unroll
        for (int i = 0; i < 4; ++i) {
            ah[i] = *(bf16x8*)&Ahs[mb + i * 16 + fr][fq8];
            al[i] = *(bf16x8*)&Als[mb + i * 16 + fr][fq8];
        }
#pragma unroll
        for (int j = 0; j < 2; ++j) {
            bh[j] = *(bf16x8*)&Bhs[nb + j * 16 + fr][fq8];
            bl[j] = *(bf16x8*)&Bls[nb + j * 16 + fr][fq8];
        }
        // ---- 3-pass MFMA (8 independent per pass) ----
#pragma unroll
        for (int i = 0; i < 4; ++i)
#pragma unroll
            for (int j = 0; j < 2; ++j)
                acc[i][j] = __builtin_amdgcn_mfma_f32_16x16x32_bf16(ah[i], bh[j], acc[i][j], 0, 0, 0);
#pragma unroll
        for (int i = 0; i < 4; ++i)
#pragma unroll
            for (int j = 0; j < 2; ++j)
                acc[i][j] = __builtin_amdgcn_mfma_f32_16x16x32_bf16(ah[i], bl[j], acc[i][j], 0, 0, 0);
#pragma unroll
        for (int i = 0; i < 4; ++i)
#pragma unroll
            for (int j = 0; j < 2; ++j)
                acc[i][j] = __builtin_amdgcn_mfma_f32_16x16x32_bf16(al[i], bh[j], acc[i][j], 0, 0, 0);
        __syncthreads();
    }

    // ---- epilogue: bias (+GELU), store. C row = (lane>>4)*4+reg, col = lane&15 ----
    const int ccol0 = n0 + nb + fr;
    const float b0 = bias[ccol0];
    const float b1 = bias[ccol0 + 16];
#pragma unroll
    for (int i = 0; i < 4; ++i) {
#pragma unroll
        for (int r = 0; r < 4; ++r) {
            int row = m0 + mb + i * 16 + fq * 4 + r;
            if (row < M) {
                float v0 = acc[i][0][r] + b0;
                float v1 = acc[i][1][r] + b1;
                if (GELU) { v0 = gelu_exact(v0); v1 = gelu_exact(v1); }
                C[(size_t)row * N + ccol0]      = v0;
                C[(size_t)row * N + ccol0 + 16] = v1;
            }
        }
    }
}

// ---------------- flash attention (fp32), 4 lanes per q-row ----------------
__global__ __launch_bounds__(256) void attn_kernel(
    const float* __restrict__ Q, const float* __restrict__ Kb,
    const float* __restrict__ Vb, float* __restrict__ O) {
    constexpr int KT = 32;
    constexpr int QT = 64;
    constexpr int LDP = 68;                 // padded row stride (floats)
    __shared__ float Kl[KT][LDP];
    __shared__ float Vl[KT][LDP];
    const int tid  = threadIdx.x;
    const int lane = tid & 63;
    const int wave = tid >> 6;
    const int s    = lane >> 4;             // dh slice 0..3 (16 floats)
    const int r_loc = wave * 16 + (lane & 15);
    const int qt = blockIdx.x, h = blockIdx.y, b = blockIdx.z;
    const int row  = qt * QT + r_loc;
    const bool active = row < L_;
    const int rowc = active ? row : (L_ - 1);
    const int col0 = h * DH_;
    const size_t qbase = ((size_t)b * L_ + rowc) * D_ + col0 + s * 16;

    float q[16];
#pragma unroll
    for (int i = 0; i < 4; ++i) {
        float4 v = *(const float4*)&Q[qbase + i * 4];
        q[4*i+0] = v.x; q[4*i+1] = v.y; q[4*i+2] = v.z; q[4*i+3] = v.w;
    }
    float o[16];
#pragma unroll
    for (int i = 0; i < 16; ++i) o[i] = 0.f;
    float m = -1e30f, l = 0.f;

    for (int kt = 0; kt < L_; kt += KT) {
#pragma unroll
        for (int rep = 0; rep < 2; ++rep) {
            int f  = tid + rep * 256;       // 0..511
            int kr = f >> 4;                // 0..31
            int cq = f & 15;
            int g  = kt + kr;
            size_t gb = ((size_t)b * L_ + (g < L_ ? g : L_ - 1)) * D_ + col0 + cq * 4;
            *(float4*)&Kl[kr][cq * 4] = *(const float4*)&Kb[gb];
            *(float4*)&Vl[kr][cq * 4] = *(const float4*)&Vb[gb];
        }
        __syncthreads();

        float p[KT];
#pragma unroll
        for (int j = 0; j < KT; ++j) {
            float4 k0 = *(float4*)&Kl[j][s * 16 + 0];
            float4 k1 = *(float4*)&Kl[j][s * 16 + 4];
            float4 k2 = *(float4*)&Kl[j][s * 16 + 8];
            float4 k3 = *(float4*)&Kl[j][s * 16 + 12];
            float t = 0.f;
            t = fmaf(q[0],  k0.x, t); t = fmaf(q[1],  k0.y, t);
            t = fmaf(q[2],  k0.z, t); t = fmaf(q[3],  k0.w, t);
            t = fmaf(q[4],  k1.x, t); t = fmaf(q[5],  k1.y, t);
            t = fmaf(q[6],  k1.z, t); t = fmaf(q[7],  k1.w, t);
            t = fmaf(q[8],  k2.x, t); t = fmaf(q[9],  k2.y, t);
            t = fmaf(q[10], k2.z, t); t = fmaf(q[11], k2.w, t);
            t = fmaf(q[12], k3.x, t); t = fmaf(q[13], k3.y, t);
            t = fmaf(q[14], k3.z, t); t = fmaf(q[15], k3.w, t);
            p[j] = t;
        }
#pragma unroll
        for (int j = 0; j < KT; ++j) {
            float t = p[j];
            t += __shfl_xor(t, 16);
            t += __shfl_xor(t, 32);
            p[j] = (kt + j < L_) ? t * SCALE_ : -1e30f;
        }
        float mt = m;
#pragma unroll
        for (int j = 0; j < KT; ++j) mt = fmaxf(mt, p[j]);
        float scl = __expf(m - mt);
        float ls = 0.f;
#pragma unroll
        for (int j = 0; j < KT; ++j) { p[j] = __expf(p[j] - mt); ls += p[j]; }
        m = mt;
        l = l * scl + ls;
#pragma unroll
        for (int i = 0; i < 16; ++i) o[i] *= scl;
#pragma unroll
        for (int j = 0; j < KT; ++j) {
            float4 v0 = *(float4*)&Vl[j][s * 16 + 0];
            float4 v1 = *(float4*)&Vl[j][s * 16 + 4];
            float4 v2 = *(float4*)&Vl[j][s * 16 + 8];
            float4 v3 = *(float4*)&Vl[j][s * 16 + 12];
            float pj = p[j];
            o[0]  = fmaf(pj, v0.x, o[0]);  o[1]  = fmaf(pj, v0.y, o[1]);
            o[2]  = fmaf(pj, v0.z, o[2]);  o[3]  = fmaf(pj, v0.w, o[3]);
            o[4]  = fmaf(pj, v1.x, o[4]);  o[5]  = fmaf(pj, v1.y, o[5]);
            o[6]  = fmaf(pj, v1.z, o[6]);  o[7]  = fmaf(pj, v1.w, o[7]);
            o[8]  = fmaf(pj, v2.x, o[8]);  o[9]  = fmaf(pj, v2.y, o[9]);
            o[10] = fmaf(pj, v2.z, o[10]); o[11] = fmaf(pj, v2.w, o[11]);
            o[12] = fmaf(pj, v3.x, o[12]); o[13] = fmaf(pj, v3.y, o[13]);
            o[14] = fmaf(pj, v3.z, o[14]); o[15] = fmaf(pj, v3.w, o[15]);
        }
        __syncthreads();
    }

    if (active) {
        float inv = 1.f / l;
#pragma unroll
        for (int i = 0; i < 4; ++i) {
            float4 v;
            v.x = o[4*i+0] * inv; v.y = o[4*i+1] * inv;
            v.z = o[4*i+2] * inv; v.w = o[4*i+3] * inv;
            *(float4*)&O[qbase + i * 4] = v;
        }
    }
}

// ---------------- fused residual add + LayerNorm ----------------
__global__ __launch_bounds__(256) void add_ln_kernel(
    const float* __restrict__ X, const float* __restrict__ Y,
    const float* __restrict__ g, const float* __restrict__ be,
    float* __restrict__ Out) {
    int wave = threadIdx.x >> 6;
    int lane = threadIdx.x & 63;
    int row = blockIdx.x * 4 + wave;
    if (row >= M_) return;
    size_t base = (size_t)row * D_;
    int c0 = lane * 4, c1 = 256 + lane * 4;
    float4 xa = *(const float4*)&X[base + c0];
    float4 xb = *(const float4*)&X[base + c1];
    float4 ya = *(const float4*)&Y[base + c0];
    float4 yb = *(const float4*)&Y[base + c1];
    float v[8] = {xa.x + ya.x, xa.y + ya.y, xa.z + ya.z, xa.w + ya.w,
                  xb.x + yb.x, xb.y + yb.y, xb.z + yb.z, xb.w + yb.w};
    float s = 0.f, s2 = 0.f;
#pragma unroll
    for (int i = 0; i < 8; ++i) { s += v[i]; s2 = fmaf(v[i], v[i], s2); }
#pragma unroll
    for (int off = 32; off > 0; off >>= 1) {
        s  += __shfl_xor(s, off);
        s2 += __shfl_xor(s2, off);
    }
    float mean = s * (1.f / D_);
    float var  = s2 * (1.f / D_) - mean * mean;
    float rstd = rsqrtf(var + EPS_);
    float4 ga = *(const float4*)&g[c0];
    float4 gb = *(const float4*)&g[c1];
    float4 ba = *(const float4*)&be[c0];
    float4 bb = *(const float4*)&be[c1];
    float4 oa, ob;
    oa.x = (v[0] - mean) * rstd * ga.x + ba.x;
    oa.y = (v[1] - mean) * rstd * ga.y + ba.y;
    oa.z = (v[2] - mean) * rstd * ga.z + ba.z;
    oa.w = (v[3] - mean) * rstd * ga.w + ba.w;
    ob.x = (v[4] - mean) * rstd * gb.x + bb.x;
    ob.y = (v[5] - mean) * rstd * gb.y + bb.y;
    ob.z = (v[6] - mean) * rstd * gb.z + bb.z;
    ob.w = (v[7] - mean) * rstd * gb.w + bb.w;
    *(float4*)&Out[base + c0] = oa;
    *(float4*)&Out[base + c1] = ob;
}

// ---------------- launch ----------------
extern "C" void kernel_launch(void* const* d_in, const int* in_sizes, int n_in,
                              void* d_out, int out_size, void* d_ws, size_t ws_size,
                              hipStream_t stream) {
    const float* embed1 = (const float*)d_in[0];
    const float* embed2 = (const float*)d_in[1];
    const float* cls    = (const float*)d_in[2];
    const float* Wq = (const float*)d_in[3];
    const float* bq = (const float*)d_in[4];
    const float* Wk = (const float*)d_in[5];
    const float* bk = (const float*)d_in[6];
    const float* Wv = (const float*)d_in[7];
    const float* bv = (const float*)d_in[8];
    const float* Wo = (const float*)d_in[9];
    const float* bo = (const float*)d_in[10];
    const float* ln1g = (const float*)d_in[11];
    const float* ln1b = (const float*)d_in[12];
    const float* W1 = (const float*)d_in[13];
    const float* b1 = (const float*)d_in[14];
    const float* W2 = (const float*)d_in[15];
    const float* b2 = (const float*)d_in[16];
    const float* ln2g = (const float*)d_in[17];
    const float* ln2b = (const float*)d_in[18];

    const size_t SZ = (size_t)M_ * D_;
    float* ws = (float*)d_ws;
    float* X  = ws;
    float* X2 = ws + SZ;
    float* Qb = ws + 2 * SZ;
    float* Kb = ws + 3 * SZ;
    float* Vb = ws + 4 * SZ;
    float* Tb = ws + 5 * SZ;
    float* Hb = ws + 6 * SZ;                 // [M, DFF]

    write_cls_kernel<<<(B_ * D_) / 256, 256, 0, stream>>>(cls, X, X2);
    transpose_embed_kernel<<<dim3(L0_ / 32, D_ / 32, B_), dim3(32, 8), 0, stream>>>(embed1, X);
    transpose_embed_kernel<<<dim3(L0_ / 32, D_ / 32, B_), dim3(32, 8), 0, stream>>>(embed2, X2);

    const int GM = (M_ + 127) / 128;         // 65
    const int g512  = GM * (512 / 64);       // 520
    const int g2048 = GM * (2048 / 64);      // 2080

    for (int l = 0; l < NLAYER_; ++l) {
        const float* Wq_l = Wq + (size_t)l * D_ * D_;
        const float* Wk_l = Wk + (size_t)l * D_ * D_;
        const float* Wv_l = Wv + (size_t)l * D_ * D_;
        const float* Wo_l = Wo + (size_t)l * D_ * D_;
        const float* W1_l = W1 + (size_t)l * DFF_ * D_;
        const float* W2_l = W2 + (size_t)l * D_ * DFF_;

        gemm_mfma_kernel<false><<<g512, 256, 0, stream>>>(
            X, Wq_l, bq + l * D_, Qb, M_, D_, D_);
        gemm_mfma_kernel<false><<<g512, 256, 0, stream>>>(
            X2, Wk_l, bk + l * D_, Kb, M_, D_, D_);
        gemm_mfma_kernel<false><<<g512, 256, 0, stream>>>(
            X2, Wv_l, bv + l * D_, Vb, M_, D_, D_);

        attn_kernel<<<dim3((L_ + 63) / 64, H_, B_), 256, 0, stream>>>(Qb, Kb, Vb, Tb);

        gemm_mfma_kernel<false><<<g512, 256, 0, stream>>>(
            Tb, Wo_l, bo + l * D_, Qb, M_, D_, D_);

        add_ln_kernel<<<(M_ + 3) / 4, 256, 0, stream>>>(
            X, Qb, ln1g + l * D_, ln1b + l * D_, X);

        gemm_mfma_kernel<true><<<g2048, 256, 0, stream>>>(
            X, W1_l, b1 + l * DFF_, Hb, M_, DFF_, D_);
        gemm_mfma_kernel<false><<<g512, 256, 0, stream>>>(
            Hb, W2_l, b2 + l * D_, Tb, M_, D_, DFF_);

        float* out_ptr = (l == NLAYER_ - 1) ? (float*)d_out : X;
        add_ln_kernel<<<(M_ + 3) / 4, 256, 0, stream>>>(
            X, Tb, ln2g + l * D_, ln2b + l * D_, out_ptr);
    }
}

// Round 5
// 1027.180 us; speedup vs baseline: 3.8925x; 1.7274x over previous
//
#include <hip/hip_runtime.h>
#include <hip/hip_bf16.h>

// ---------------- problem constants ----------------
constexpr int B_   = 8;
constexpr int D_   = 512;
constexpr int L0_  = 1024;
constexpr int L_   = 1025;          // L0 + cls
constexpr int H_   = 8;
constexpr int DH_  = 64;
constexpr int DFF_ = 2048;
constexpr int NLAYER_ = 2;
constexpr int M_   = B_ * L_;       // 8200 rows
constexpr float EPS_   = 1e-6f;
constexpr float SCALE_ = 0.125f;    // 1/sqrt(64)

#define DEV_INLINE __device__ __forceinline__

typedef __attribute__((ext_vector_type(8))) __bf16 bf16x8;
typedef __attribute__((ext_vector_type(4))) __bf16 bf16x4;
typedef __attribute__((ext_vector_type(4))) float  f32x4;

DEV_INLINE float gelu_exact(float x) {
    return 0.5f * x * (1.f + erff(x * 0.70710678118654752f));
}

struct bfpair { __bf16 h, l; };
// split fp32 into bf16 hi + bf16 lo (v ≈ h + l, residual ~2^-18 |v|)
DEV_INLINE bfpair split_bf(float v) {
    bfpair p;
    p.h = (__bf16)v;
    p.l = (__bf16)(v - (float)p.h);
    return p;
}

// ---------------- build x1/x2 ----------------
__global__ __launch_bounds__(256) void write_cls_kernel(
    const float* __restrict__ cls, float* __restrict__ X1, float* __restrict__ X2) {
    int idx = blockIdx.x * 256 + threadIdx.x;      // 0 .. 8*512-1
    int b = idx >> 9;
    int d = idx & 511;
    float v = cls[d];
    X1[(size_t)b * L_ * D_ + d] = v;
    X2[(size_t)b * L_ * D_ + d] = v;
}

// embed [B, D, L0] -> X rows 1..L0
__global__ __launch_bounds__(256) void transpose_embed_kernel(
    const float* __restrict__ e, float* __restrict__ X) {
    __shared__ float tile[32][33];
    int b  = blockIdx.z;
    int i0 = blockIdx.x * 32;       // along L0
    int d0 = blockIdx.y * 32;       // along D
    int tx = threadIdx.x;           // 0..31
    int ty = threadIdx.y;           // 0..7
#pragma unroll
    for (int j = 0; j < 32; j += 8)
        tile[ty + j][tx] = e[((size_t)b * D_ + d0 + ty + j) * L0_ + i0 + tx];
    __syncthreads();
#pragma unroll
    for (int j = 0; j < 32; j += 8)
        X[((size_t)b * L_ + 1 + i0 + ty + j) * D_ + d0 + tx] = tile[tx][ty + j];
}

// ---------------- split-bf16 MFMA GEMM ----------------
// C[M,N] = A[M,K] * W[N,K]^T + bias[N], fp32 in/out, internally 3-pass
// split-bf16 (hi*hi + hi*lo + lo*hi) via v_mfma_f32_16x16x32_bf16.
template <bool GELU>
__global__ __launch_bounds__(256) void gemm_mfma_kernel(
    const float* __restrict__ A, const float* __restrict__ W,
    const float* __restrict__ bias, float* __restrict__ C,
    int M, int N, int K) {
    constexpr int BM = 128, BN = 64, BK = 32;
    constexpr int LDK = BK + 8;   // 40 bf16 = 80B row stride (bank-friendly)
    __shared__ alignas(16) __bf16 Ahs[BM][LDK];
    __shared__ alignas(16) __bf16 Als[BM][LDK];
    __shared__ alignas(16) __bf16 Bhs[BN][LDK];
    __shared__ alignas(16) __bf16 Bls[BN][LDK];

    const int GM = (M + BM - 1) / BM;
    // bijective XCD swizzle over the flat grid
    const int nwg = gridDim.x;
    int bid = blockIdx.x;
    {
        int q = nwg >> 3, r = nwg & 7;
        int xcd = bid & 7, pos = bid >> 3;
        bid = (xcd < r) ? xcd * (q + 1) + pos
                        : r * (q + 1) + (xcd - r) * q + pos;
    }
    const int bn = bid / GM;
    const int bm = bid % GM;
    const int m0 = bm * BM;
    const int n0 = bn * BN;

    const int tid  = threadIdx.x;
    const int lane = tid & 63;
    const int wv   = tid >> 6;
    const int wr   = wv >> 1;          // 0..1 (m half)
    const int wc   = wv & 1;           // 0..1 (n half)
    const int fr   = lane & 15;
    const int fq   = lane >> 4;        // 0..3
    const int fq8  = fq * 8;
    const int mb   = wr * 64;
    const int nb   = wc * 32;

    const int srow = tid >> 3;
    const int sq   = tid & 7;
    size_t aOff[4], wOff[2];
#pragma unroll
    for (int rep = 0; rep < 4; ++rep) {
        int r = m0 + srow + rep * 32;
        if (r > M - 1) r = M - 1;
        aOff[rep] = (size_t)r * K + sq * 4;
    }
#pragma unroll
    for (int rep = 0; rep < 2; ++rep)
        wOff[rep] = (size_t)(n0 + srow + rep * 32) * K + sq * 4;

    f32x4 acc[4][2];
#pragma unroll
    for (int i = 0; i < 4; ++i)
#pragma unroll
        for (int j = 0; j < 2; ++j) acc[i][j] = (f32x4){0.f, 0.f, 0.f, 0.f};

    const int nk = K / BK;
    float4 aR[4], wR[2];
#pragma unroll
    for (int rep = 0; rep < 4; ++rep) aR[rep] = *(const float4*)&A[aOff[rep]];
#pragma unroll
    for (int rep = 0; rep < 2; ++rep) wR[rep] = *(const float4*)&W[wOff[rep]];

    for (int kt = 0; kt < nk; ++kt) {
#pragma unroll
        for (int rep = 0; rep < 4; ++rep) {
            int row = srow + rep * 32;
            bf16x4 h, l;
            bfpair p0 = split_bf(aR[rep].x); h[0] = p0.h; l[0] = p0.l;
            bfpair p1 = split_bf(aR[rep].y); h[1] = p1.h; l[1] = p1.l;
            bfpair p2 = split_bf(aR[rep].z); h[2] = p2.h; l[2] = p2.l;
            bfpair p3 = split_bf(aR[rep].w); h[3] = p3.h; l[3] = p3.l;
            *(bf16x4*)&Ahs[row][sq * 4] = h;
            *(bf16x4*)&Als[row][sq * 4] = l;
        }
#pragma unroll
        for (int rep = 0; rep < 2; ++rep) {
            int row = srow + rep * 32;
            bf16x4 h, l;
            bfpair p0 = split_bf(wR[rep].x); h[0] = p0.h; l[0] = p0.l;
            bfpair p1 = split_bf(wR[rep].y); h[1] = p1.h; l[1] = p1.l;
            bfpair p2 = split_bf(wR[rep].z); h[2] = p2.h; l[2] = p2.l;
            bfpair p3 = split_bf(wR[rep].w); h[3] = p3.h; l[3] = p3.l;
            *(bf16x4*)&Bhs[row][sq * 4] = h;
            *(bf16x4*)&Bls[row][sq * 4] = l;
        }
        __syncthreads();

        if (kt + 1 < nk) {
            int k0 = (kt + 1) * BK;
#pragma unroll
            for (int rep = 0; rep < 4; ++rep) aR[rep] = *(const float4*)&A[aOff[rep] + k0];
#pragma unroll
            for (int rep = 0; rep < 2; ++rep) wR[rep] = *(const float4*)&W[wOff[rep] + k0];
        }

        bf16x8 ah[4], al[4], bh[2], bl[2];
#pragma unroll
        for (int i = 0; i < 4; ++i) {
            ah[i] = *(bf16x8*)&Ahs[mb + i * 16 + fr][fq8];
            al[i] = *(bf16x8*)&Als[mb + i * 16 + fr][fq8];
        }
#pragma unroll
        for (int j = 0; j < 2; ++j) {
            bh[j] = *(bf16x8*)&Bhs[nb + j * 16 + fr][fq8];
            bl[j] = *(bf16x8*)&Bls[nb + j * 16 + fr][fq8];
        }
#pragma unroll
        for (int i = 0; i < 4; ++i)
#pragma unroll
            for (int j = 0; j < 2; ++j)
                acc[i][j] = __builtin_amdgcn_mfma_f32_16x16x32_bf16(ah[i], bh[j], acc[i][j], 0, 0, 0);
#pragma unroll
        for (int i = 0; i < 4; ++i)
#pragma unroll
            for (int j = 0; j < 2; ++j)
                acc[i][j] = __builtin_amdgcn_mfma_f32_16x16x32_bf16(ah[i], bl[j], acc[i][j], 0, 0, 0);
#pragma unroll
        for (int i = 0; i < 4; ++i)
#pragma unroll
            for (int j = 0; j < 2; ++j)
                acc[i][j] = __builtin_amdgcn_mfma_f32_16x16x32_bf16(al[i], bh[j], acc[i][j], 0, 0, 0);
        __syncthreads();
    }

    const int ccol0 = n0 + nb + fr;
    const float b0 = bias[ccol0];
    const float b1 = bias[ccol0 + 16];
#pragma unroll
    for (int i = 0; i < 4; ++i) {
#pragma unroll
        for (int r = 0; r < 4; ++r) {
            int row = m0 + mb + i * 16 + fq * 4 + r;
            if (row < M) {
                float v0 = acc[i][0][r] + b0;
                float v1 = acc[i][1][r] + b1;
                if (GELU) { v0 = gelu_exact(v0); v1 = gelu_exact(v1); }
                C[(size_t)row * N + ccol0]      = v0;
                C[(size_t)row * N + ccol0 + 16] = v1;
            }
        }
    }
}

// ---------------- MFMA flash attention (split-bf16, fp32 accumulate) ----------------
// grid (17, H, B), block 256 = 4 waves. Q-tile 64 rows; K/V tiles 64 rows.
// Wave w owns S/O rows 16w..16w+15. 3-pass split-bf16 on QK^T and PV.
__global__ __launch_bounds__(256) void attn_mfma_kernel(
    const float* __restrict__ Q, const float* __restrict__ Kb,
    const float* __restrict__ Vb, float* __restrict__ O) {
    constexpr int LDP = 72;     // bf16 row stride: 144B (16B-aligned, bank-friendly)
    __shared__ alignas(16) __bf16 Qh[64][LDP], Ql[64][LDP];
    __shared__ alignas(16) __bf16 Kh[64][LDP], Kl[64][LDP];
    __shared__ alignas(16) __bf16 Vth[64][LDP], Vtl[64][LDP];
    __shared__ alignas(16) __bf16 Ph[64][LDP], Pl[64][LDP];

    const int tid  = threadIdx.x;
    const int lane = tid & 63;
    const int wv   = tid >> 6;
    const int fr   = lane & 15;
    const int fq   = lane >> 4;
    const int fq8  = fq * 8;
    const int qt = blockIdx.x, h = blockIdx.y, b = blockIdx.z;
    const int q0 = qt * 64;
    const size_t base = (size_t)b * L_ * D_ + h * DH_;

    // ---- stage Q tile (split hi/lo) ----
#pragma unroll
    for (int rep = 0; rep < 4; ++rep) {
        int f = tid + rep * 256;       // 0..1023
        int r = f >> 4, cq = f & 15;
        int gr = q0 + r; if (gr > L_ - 1) gr = L_ - 1;
        float4 v = *(const float4*)&Q[base + (size_t)gr * D_ + cq * 4];
        bf16x4 hh, ll;
        bfpair p0 = split_bf(v.x); hh[0] = p0.h; ll[0] = p0.l;
        bfpair p1 = split_bf(v.y); hh[1] = p1.h; ll[1] = p1.l;
        bfpair p2 = split_bf(v.z); hh[2] = p2.h; ll[2] = p2.l;
        bfpair p3 = split_bf(v.w); hh[3] = p3.h; ll[3] = p3.l;
        *(bf16x4*)&Qh[r][cq * 4] = hh;
        *(bf16x4*)&Ql[r][cq * 4] = ll;
    }

    float m[4], l[4];
#pragma unroll
    for (int i = 0; i < 4; ++i) { m[i] = -1e30f; l[i] = 0.f; }
    f32x4 oA[4];
#pragma unroll
    for (int c = 0; c < 4; ++c) oA[c] = (f32x4){0.f, 0.f, 0.f, 0.f};

    for (int kt = 0; kt < L_; kt += 64) {
        __syncthreads();      // prev tile's LDS reads done (also Q staged, iter 0)
        // ---- stage K (row-major) and V (transposed) tiles, split hi/lo ----
#pragma unroll
        for (int rep = 0; rep < 4; ++rep) {
            int f = tid + rep * 256;
            int r = f >> 4, cq = f & 15;
            int gr = kt + r; if (gr > L_ - 1) gr = L_ - 1;
            size_t ga = base + (size_t)gr * D_ + cq * 4;
            float4 kv = *(const float4*)&Kb[ga];
            float4 vv = *(const float4*)&Vb[ga];
            bf16x4 hh, ll;
            bfpair p0 = split_bf(kv.x); hh[0] = p0.h; ll[0] = p0.l;
            bfpair p1 = split_bf(kv.y); hh[1] = p1.h; ll[1] = p1.l;
            bfpair p2 = split_bf(kv.z); hh[2] = p2.h; ll[2] = p2.l;
            bfpair p3 = split_bf(kv.w); hh[3] = p3.h; ll[3] = p3.l;
            *(bf16x4*)&Kh[r][cq * 4] = hh;
            *(bf16x4*)&Kl[r][cq * 4] = ll;
            bfpair q0p = split_bf(vv.x); Vth[cq * 4 + 0][r] = q0p.h; Vtl[cq * 4 + 0][r] = q0p.l;
            bfpair q1p = split_bf(vv.y); Vth[cq * 4 + 1][r] = q1p.h; Vtl[cq * 4 + 1][r] = q1p.l;
            bfpair q2p = split_bf(vv.z); Vth[cq * 4 + 2][r] = q2p.h; Vtl[cq * 4 + 2][r] = q2p.l;
            bfpair q3p = split_bf(vv.w); Vth[cq * 4 + 3][r] = q3p.h; Vtl[cq * 4 + 3][r] = q3p.l;
        }
        __syncthreads();

        // ---- S slice = Q[16wv..+15] · K^T  (3-pass split) ----
        bf16x8 aqh[2], aql[2];
        aqh[0] = *(bf16x8*)&Qh[16 * wv + fr][fq8];
        aqh[1] = *(bf16x8*)&Qh[16 * wv + fr][32 + fq8];
        aql[0] = *(bf16x8*)&Ql[16 * wv + fr][fq8];
        aql[1] = *(bf16x8*)&Ql[16 * wv + fr][32 + fq8];
        float p[4][4];
#pragma unroll
        for (int c = 0; c < 4; ++c) {
            bf16x8 bh0 = *(bf16x8*)&Kh[16 * c + fr][fq8];
            bf16x8 bh1 = *(bf16x8*)&Kh[16 * c + fr][32 + fq8];
            bf16x8 bl0 = *(bf16x8*)&Kl[16 * c + fr][fq8];
            bf16x8 bl1 = *(bf16x8*)&Kl[16 * c + fr][32 + fq8];
            f32x4 s = (f32x4){0.f, 0.f, 0.f, 0.f};
            s = __builtin_amdgcn_mfma_f32_16x16x32_bf16(aqh[0], bh0, s, 0, 0, 0);
            s = __builtin_amdgcn_mfma_f32_16x16x32_bf16(aqh[1], bh1, s, 0, 0, 0);
            s = __builtin_amdgcn_mfma_f32_16x16x32_bf16(aqh[0], bl0, s, 0, 0, 0);
            s = __builtin_amdgcn_mfma_f32_16x16x32_bf16(aqh[1], bl1, s, 0, 0, 0);
            s = __builtin_amdgcn_mfma_f32_16x16x32_bf16(aql[0], bh0, s, 0, 0, 0);
            s = __builtin_amdgcn_mfma_f32_16x16x32_bf16(aql[1], bh1, s, 0, 0, 0);
            const bool valid = (kt + 16 * c + fr) < L_;
#pragma unroll
            for (int rr = 0; rr < 4; ++rr)
                p[c][rr] = valid ? s[rr] * SCALE_ : -1e30f;
        }

        // ---- online softmax (row r = fq*4+rr lives in this 16-lane group) ----
        float tmax[4];
#pragma unroll
        for (int rr = 0; rr < 4; ++rr)
            tmax[rr] = fmaxf(fmaxf(p[0][rr], p[1][rr]), fmaxf(p[2][rr], p[3][rr]));
#pragma unroll
        for (int off = 1; off <= 8; off <<= 1)
#pragma unroll
            for (int rr = 0; rr < 4; ++rr)
                tmax[rr] = fmaxf(tmax[rr], __shfl_xor(tmax[rr], off));
        float scl[4];
#pragma unroll
        for (int rr = 0; rr < 4; ++rr) {
            float mn = fmaxf(m[rr], tmax[rr]);
            scl[rr] = __expf(m[rr] - mn);
            m[rr] = mn;
        }
        float ls[4] = {0.f, 0.f, 0.f, 0.f};
#pragma unroll
        for (int c = 0; c < 4; ++c)
#pragma unroll
            for (int rr = 0; rr < 4; ++rr) {
                float e = __expf(p[c][rr] - m[rr]);
                p[c][rr] = e;
                ls[rr] += e;
            }
#pragma unroll
        for (int off = 1; off <= 8; off <<= 1)
#pragma unroll
            for (int rr = 0; rr < 4; ++rr) ls[rr] += __shfl_xor(ls[rr], off);
#pragma unroll
        for (int rr = 0; rr < 4; ++rr) l[rr] = l[rr] * scl[rr] + ls[rr];
#pragma unroll
        for (int c = 0; c < 4; ++c)
#pragma unroll
            for (int rr = 0; rr < 4; ++rr) oA[c][rr] *= scl[rr];

        // ---- write P slice (own rows only -> no cross-wave barrier) ----
#pragma unroll
        for (int c = 0; c < 4; ++c)
#pragma unroll
            for (int rr = 0; rr < 4; ++rr) {
                bfpair pp = split_bf(p[c][rr]);
                Ph[16 * wv + fq * 4 + rr][16 * c + fr] = pp.h;
                Pl[16 * wv + fq * 4 + rr][16 * c + fr] = pp.l;
            }

        // ---- O += P · V (3-pass split) ----
        bf16x8 aph[2], apl[2];
        aph[0] = *(bf16x8*)&Ph[16 * wv + fr][fq8];
        aph[1] = *(bf16x8*)&Ph[16 * wv + fr][32 + fq8];
        apl[0] = *(bf16x8*)&Pl[16 * wv + fr][fq8];
        apl[1] = *(bf16x8*)&Pl[16 * wv + fr][32 + fq8];
#pragma unroll
        for (int c = 0; c < 4; ++c) {
            bf16x8 bh0 = *(bf16x8*)&Vth[16 * c + fr][fq8];
            bf16x8 bh1 = *(bf16x8*)&Vth[16 * c + fr][32 + fq8];
            bf16x8 bl0 = *(bf16x8*)&Vtl[16 * c + fr][fq8];
            bf16x8 bl1 = *(bf16x8*)&Vtl[16 * c + fr][32 + fq8];
            f32x4 o = oA[c];
            o = __builtin_amdgcn_mfma_f32_16x16x32_bf16(aph[0], bh0, o, 0, 0, 0);
            o = __builtin_amdgcn_mfma_f32_16x16x32_bf16(aph[1], bh1, o, 0, 0, 0);
            o = __builtin_amdgcn_mfma_f32_16x16x32_bf16(aph[0], bl0, o, 0, 0, 0);
            o = __builtin_amdgcn_mfma_f32_16x16x32_bf16(aph[1], bl1, o, 0, 0, 0);
            o = __builtin_amdgcn_mfma_f32_16x16x32_bf16(apl[0], bh0, o, 0, 0, 0);
            o = __builtin_amdgcn_mfma_f32_16x16x32_bf16(apl[1], bh1, o, 0, 0, 0);
            oA[c] = o;
        }
    }

    // ---- epilogue ----
    float inv[4];
#pragma unroll
    for (int rr = 0; rr < 4; ++rr) inv[rr] = 1.f / l[rr];
#pragma unroll
    for (int rr = 0; rr < 4; ++rr) {
        int row = q0 + 16 * wv + fq * 4 + rr;
        if (row < L_) {
#pragma unroll
            for (int c = 0; c < 4; ++c)
                O[base + (size_t)row * D_ + 16 * c + fr] = oA[c][rr] * inv[rr];
        }
    }
}

// ---------------- fused residual add + LayerNorm ----------------
__global__ __launch_bounds__(256) void add_ln_kernel(
    const float* __restrict__ X, const float* __restrict__ Y,
    const float* __restrict__ g, const float* __restrict__ be,
    float* __restrict__ Out) {
    int wave = threadIdx.x >> 6;
    int lane = threadIdx.x & 63;
    int row = blockIdx.x * 4 + wave;
    if (row >= M_) return;
    size_t base = (size_t)row * D_;
    int c0 = lane * 4, c1 = 256 + lane * 4;
    float4 xa = *(const float4*)&X[base + c0];
    float4 xb = *(const float4*)&X[base + c1];
    float4 ya = *(const float4*)&Y[base + c0];
    float4 yb = *(const float4*)&Y[base + c1];
    float v[8] = {xa.x + ya.x, xa.y + ya.y, xa.z + ya.z, xa.w + ya.w,
                  xb.x + yb.x, xb.y + yb.y, xb.z + yb.z, xb.w + yb.w};
    float s = 0.f, s2 = 0.f;
#pragma unroll
    for (int i = 0; i < 8; ++i) { s += v[i]; s2 = fmaf(v[i], v[i], s2); }
#pragma unroll
    for (int off = 32; off > 0; off >>= 1) {
        s  += __shfl_xor(s, off);
        s2 += __shfl_xor(s2, off);
    }
    float mean = s * (1.f / D_);
    float var  = s2 * (1.f / D_) - mean * mean;
    float rstd = rsqrtf(var + EPS_);
    float4 ga = *(const float4*)&g[c0];
    float4 gb = *(const float4*)&g[c1];
    float4 ba = *(const float4*)&be[c0];
    float4 bb = *(const float4*)&be[c1];
    float4 oa, ob;
    oa.x = (v[0] - mean) * rstd * ga.x + ba.x;
    oa.y = (v[1] - mean) * rstd * ga.y + ba.y;
    oa.z = (v[2] - mean) * rstd * ga.z + ba.z;
    oa.w = (v[3] - mean) * rstd * ga.w + ba.w;
    ob.x = (v[4] - mean) * rstd * gb.x + bb.x;
    ob.y = (v[5] - mean) * rstd * gb.y + bb.y;
    ob.z = (v[6] - mean) * rstd * gb.z + bb.z;
    ob.w = (v[7] - mean) * rstd * gb.w + bb.w;
    *(float4*)&Out[base + c0] = oa;
    *(float4*)&Out[base + c1] = ob;
}

// ---------------- launch ----------------
extern "C" void kernel_launch(void* const* d_in, const int* in_sizes, int n_in,
                              void* d_out, int out_size, void* d_ws, size_t ws_size,
                              hipStream_t stream) {
    const float* embed1 = (const float*)d_in[0];
    const float* embed2 = (const float*)d_in[1];
    const float* cls    = (const float*)d_in[2];
    const float* Wq = (const float*)d_in[3];
    const float* bq = (const float*)d_in[4];
    const float* Wk = (const float*)d_in[5];
    const float* bk = (const float*)d_in[6];
    const float* Wv = (const float*)d_in[7];
    const float* bv = (const float*)d_in[8];
    const float* Wo = (const float*)d_in[9];
    const float* bo = (const float*)d_in[10];
    const float* ln1g = (const float*)d_in[11];
    const float* ln1b = (const float*)d_in[12];
    const float* W1 = (const float*)d_in[13];
    const float* b1 = (const float*)d_in[14];
    const float* W2 = (const float*)d_in[15];
    const float* b2 = (const float*)d_in[16];
    const float* ln2g = (const float*)d_in[17];
    const float* ln2b = (const float*)d_in[18];

    const size_t SZ = (size_t)M_ * D_;
    float* ws = (float*)d_ws;
    float* X  = ws;
    float* X2 = ws + SZ;
    float* Qb = ws + 2 * SZ;
    float* Kb = ws + 3 * SZ;
    float* Vb = ws + 4 * SZ;
    float* Tb = ws + 5 * SZ;
    float* Hb = ws + 6 * SZ;                 // [M, DFF]

    write_cls_kernel<<<(B_ * D_) / 256, 256, 0, stream>>>(cls, X, X2);
    transpose_embed_kernel<<<dim3(L0_ / 32, D_ / 32, B_), dim3(32, 8), 0, stream>>>(embed1, X);
    transpose_embed_kernel<<<dim3(L0_ / 32, D_ / 32, B_), dim3(32, 8), 0, stream>>>(embed2, X2);

    const int GM = (M_ + 127) / 128;         // 65
    const int g512  = GM * (512 / 64);       // 520
    const int g2048 = GM * (2048 / 64);      // 2080

    for (int l = 0; l < NLAYER_; ++l) {
        const float* Wq_l = Wq + (size_t)l * D_ * D_;
        const float* Wk_l = Wk + (size_t)l * D_ * D_;
        const float* Wv_l = Wv + (size_t)l * D_ * D_;
        const float* Wo_l = Wo + (size_t)l * D_ * D_;
        const float* W1_l = W1 + (size_t)l * DFF_ * D_;
        const float* W2_l = W2 + (size_t)l * D_ * DFF_;

        gemm_mfma_kernel<false><<<g512, 256, 0, stream>>>(
            X, Wq_l, bq + l * D_, Qb, M_, D_, D_);
        gemm_mfma_kernel<false><<<g512, 256, 0, stream>>>(
            X2, Wk_l, bk + l * D_, Kb, M_, D_, D_);
        gemm_mfma_kernel<false><<<g512, 256, 0, stream>>>(
            X2, Wv_l, bv + l * D_, Vb, M_, D_, D_);

        attn_mfma_kernel<<<dim3((L_ + 63) / 64, H_, B_), 256, 0, stream>>>(Qb, Kb, Vb, Tb);

        gemm_mfma_kernel<false><<<g512, 256, 0, stream>>>(
            Tb, Wo_l, bo + l * D_, Qb, M_, D_, D_);

        add_ln_kernel<<<(M_ + 3) / 4, 256, 0, stream>>>(
            X, Qb, ln1g + l * D_, ln1b + l * D_, X);

        gemm_mfma_kernel<true><<<g2048, 256, 0, stream>>>(
            X, W1_l, b1 + l * DFF_, Hb, M_, DFF_, D_);
        gemm_mfma_kernel<false><<<g512, 256, 0, stream>>>(
            Hb, W2_l, b2 + l * D_, Tb, M_, D_, DFF_);

        float* out_ptr = (l == NLAYER_ - 1) ? (float*)d_out : X;
        add_ln_kernel<<<(M_ + 3) / 4, 256, 0, stream>>>(
            X, Tb, ln2g + l * D_, ln2b + l * D_, out_ptr);
    }
}

// Round 6
// 940.012 us; speedup vs baseline: 4.2534x; 1.0927x over previous
//
#include <hip/hip_runtime.h>
#include <hip/hip_bf16.h>

// ---------------- problem constants ----------------
constexpr int B_   = 8;
constexpr int D_   = 512;
constexpr int L0_  = 1024;
constexpr int L_   = 1025;          // L0 + cls
constexpr int H_   = 8;
constexpr int DH_  = 64;
constexpr int DFF_ = 2048;
constexpr int NLAYER_ = 2;
constexpr int M_   = B_ * L_;       // 8200 rows
constexpr int LP_  = 1088;          // padded L for Vt (17*64, rows 16B-aligned)
constexpr float EPS_   = 1e-6f;
constexpr float SCALE_ = 0.125f;    // 1/sqrt(64)

#define DEV_INLINE __device__ __forceinline__

typedef __attribute__((ext_vector_type(8))) __bf16 bf16x8;
typedef __attribute__((ext_vector_type(4))) __bf16 bf16x4;
typedef __attribute__((ext_vector_type(4))) float  f32x4;

union U4 { uint32_t u[4]; bf16x8 f; };

DEV_INLINE float gelu_exact(float x) {
    return 0.5f * x * (1.f + erff(x * 0.70710678118654752f));
}

struct bfpair { __bf16 h, l; };
DEV_INLINE bfpair split_bf(float v) {
    bfpair p;
    p.h = (__bf16)v;
    p.l = (__bf16)(v - (float)p.h);
    return p;
}
DEV_INLINE uint16_t bfbits(float v) {
    __bf16 h = (__bf16)v;
    return __builtin_bit_cast(uint16_t, h);
}
DEV_INLINE uint32_t pk2f(float a, float b) {
    return (uint32_t)bfbits(a) | ((uint32_t)bfbits(b) << 16);
}
DEV_INLINE float bflo(float v) { return v - (float)((__bf16)v); }

// ---------------- build x1/x2 ----------------
__global__ __launch_bounds__(256) void write_cls_kernel(
    const float* __restrict__ cls, float* __restrict__ X1, float* __restrict__ X2) {
    int idx = blockIdx.x * 256 + threadIdx.x;
    int b = idx >> 9;
    int d = idx & 511;
    float v = cls[d];
    X1[(size_t)b * L_ * D_ + d] = v;
    X2[(size_t)b * L_ * D_ + d] = v;
}

// embed [B, D, L0] -> X rows 1..L0
__global__ __launch_bounds__(256) void transpose_embed_kernel(
    const float* __restrict__ e, float* __restrict__ X) {
    __shared__ float tile[32][33];
    int b  = blockIdx.z;
    int i0 = blockIdx.x * 32;
    int d0 = blockIdx.y * 32;
    int tx = threadIdx.x;
    int ty = threadIdx.y;
#pragma unroll
    for (int j = 0; j < 32; j += 8)
        tile[ty + j][tx] = e[((size_t)b * D_ + d0 + ty + j) * L0_ + i0 + tx];
    __syncthreads();
#pragma unroll
    for (int j = 0; j < 32; j += 8)
        X[((size_t)b * L_ + 1 + i0 + ty + j) * D_ + d0 + tx] = tile[tx][ty + j];
}

// V [B,L,D] -> Vt [B*H, DH, LP_]  (zero-padded beyond L)
__global__ __launch_bounds__(256) void transpose_v_kernel(
    const float* __restrict__ V, float* __restrict__ Vt) {
    __shared__ float tile[32][33];
    int bh = blockIdx.z;            // b*H + h
    int l0 = blockIdx.x * 32;       // 0..1087
    int d0 = blockIdx.y * 32;       // 0 or 32
    int b = bh >> 3, h = bh & 7;
    int tx = threadIdx.x, ty = threadIdx.y;
#pragma unroll
    for (int j = 0; j < 32; j += 8) {
        int l = l0 + ty + j;
        float v = 0.f;
        if (l < L_) v = V[((size_t)b * L_ + l) * D_ + h * DH_ + d0 + tx];
        tile[ty + j][tx] = v;
    }
    __syncthreads();
#pragma unroll
    for (int j = 0; j < 32; j += 8)
        Vt[((size_t)bh * DH_ + d0 + ty + j) * LP_ + l0 + tx] = tile[tx][ty + j];
}

// ---------------- split-bf16 MFMA GEMM ----------------
template <bool GELU>
__global__ __launch_bounds__(256) void gemm_mfma_kernel(
    const float* __restrict__ A, const float* __restrict__ W,
    const float* __restrict__ bias, float* __restrict__ C,
    int M, int N, int K) {
    constexpr int BM = 128, BN = 64, BK = 32;
    constexpr int LDK = BK + 8;
    __shared__ alignas(16) __bf16 Ahs[BM][LDK];
    __shared__ alignas(16) __bf16 Als[BM][LDK];
    __shared__ alignas(16) __bf16 Bhs[BN][LDK];
    __shared__ alignas(16) __bf16 Bls[BN][LDK];

    const int GM = (M + BM - 1) / BM;
    const int nwg = gridDim.x;
    int bid = blockIdx.x;
    {
        int q = nwg >> 3, r = nwg & 7;
        int xcd = bid & 7, pos = bid >> 3;
        bid = (xcd < r) ? xcd * (q + 1) + pos
                        : r * (q + 1) + (xcd - r) * q + pos;
    }
    const int bn = bid / GM;
    const int bm = bid % GM;
    const int m0 = bm * BM;
    const int n0 = bn * BN;

    const int tid  = threadIdx.x;
    const int lane = tid & 63;
    const int wv   = tid >> 6;
    const int wr   = wv >> 1;
    const int wc   = wv & 1;
    const int fr   = lane & 15;
    const int fq   = lane >> 4;
    const int fq8  = fq * 8;
    const int mb   = wr * 64;
    const int nb   = wc * 32;

    const int srow = tid >> 3;
    const int sq   = tid & 7;
    size_t aOff[4], wOff[2];
#pragma unroll
    for (int rep = 0; rep < 4; ++rep) {
        int r = m0 + srow + rep * 32;
        if (r > M - 1) r = M - 1;
        aOff[rep] = (size_t)r * K + sq * 4;
    }
#pragma unroll
    for (int rep = 0; rep < 2; ++rep)
        wOff[rep] = (size_t)(n0 + srow + rep * 32) * K + sq * 4;

    f32x4 acc[4][2];
#pragma unroll
    for (int i = 0; i < 4; ++i)
#pragma unroll
        for (int j = 0; j < 2; ++j) acc[i][j] = (f32x4){0.f, 0.f, 0.f, 0.f};

    const int nk = K / BK;
    float4 aR[4], wR[2];
#pragma unroll
    for (int rep = 0; rep < 4; ++rep) aR[rep] = *(const float4*)&A[aOff[rep]];
#pragma unroll
    for (int rep = 0; rep < 2; ++rep) wR[rep] = *(const float4*)&W[wOff[rep]];

    for (int kt = 0; kt < nk; ++kt) {
#pragma unroll
        for (int rep = 0; rep < 4; ++rep) {
            int row = srow + rep * 32;
            bf16x4 h, l;
            bfpair p0 = split_bf(aR[rep].x); h[0] = p0.h; l[0] = p0.l;
            bfpair p1 = split_bf(aR[rep].y); h[1] = p1.h; l[1] = p1.l;
            bfpair p2 = split_bf(aR[rep].z); h[2] = p2.h; l[2] = p2.l;
            bfpair p3 = split_bf(aR[rep].w); h[3] = p3.h; l[3] = p3.l;
            *(bf16x4*)&Ahs[row][sq * 4] = h;
            *(bf16x4*)&Als[row][sq * 4] = l;
        }
#pragma unroll
        for (int rep = 0; rep < 2; ++rep) {
            int row = srow + rep * 32;
            bf16x4 h, l;
            bfpair p0 = split_bf(wR[rep].x); h[0] = p0.h; l[0] = p0.l;
            bfpair p1 = split_bf(wR[rep].y); h[1] = p1.h; l[1] = p1.l;
            bfpair p2 = split_bf(wR[rep].z); h[2] = p2.h; l[2] = p2.l;
            bfpair p3 = split_bf(wR[rep].w); h[3] = p3.h; l[3] = p3.l;
            *(bf16x4*)&Bhs[row][sq * 4] = h;
            *(bf16x4*)&Bls[row][sq * 4] = l;
        }
        __syncthreads();

        if (kt + 1 < nk) {
            int k0 = (kt + 1) * BK;
#pragma unroll
            for (int rep = 0; rep < 4; ++rep) aR[rep] = *(const float4*)&A[aOff[rep] + k0];
#pragma unroll
            for (int rep = 0; rep < 2; ++rep) wR[rep] = *(const float4*)&W[wOff[rep] + k0];
        }

        bf16x8 ah[4], al[4], bh[2], bl[2];
#pragma unroll
        for (int i = 0; i < 4; ++i) {
            ah[i] = *(bf16x8*)&Ahs[mb + i * 16 + fr][fq8];
            al[i] = *(bf16x8*)&Als[mb + i * 16 + fr][fq8];
        }
#pragma unroll
        for (int j = 0; j < 2; ++j) {
            bh[j] = *(bf16x8*)&Bhs[nb + j * 16 + fr][fq8];
            bl[j] = *(bf16x8*)&Bls[nb + j * 16 + fr][fq8];
        }
#pragma unroll
        for (int i = 0; i < 4; ++i)
#pragma unroll
            for (int j = 0; j < 2; ++j)
                acc[i][j] = __builtin_amdgcn_mfma_f32_16x16x32_bf16(ah[i], bh[j], acc[i][j], 0, 0, 0);
#pragma unroll
        for (int i = 0; i < 4; ++i)
#pragma unroll
            for (int j = 0; j < 2; ++j)
                acc[i][j] = __builtin_amdgcn_mfma_f32_16x16x32_bf16(ah[i], bl[j], acc[i][j], 0, 0, 0);
#pragma unroll
        for (int i = 0; i < 4; ++i)
#pragma unroll
            for (int j = 0; j < 2; ++j)
                acc[i][j] = __builtin_amdgcn_mfma_f32_16x16x32_bf16(al[i], bh[j], acc[i][j], 0, 0, 0);
        __syncthreads();
    }

    const int ccol0 = n0 + nb + fr;
    const float b0 = bias[ccol0];
    const float b1 = bias[ccol0 + 16];
#pragma unroll
    for (int i = 0; i < 4; ++i) {
#pragma unroll
        for (int r = 0; r < 4; ++r) {
            int row = m0 + mb + i * 16 + fq * 4 + r;
            if (row < M) {
                float v0 = acc[i][0][r] + b0;
                float v1 = acc[i][1][r] + b1;
                if (GELU) { v0 = gelu_exact(v0); v1 = gelu_exact(v1); }
                C[(size_t)row * N + ccol0]      = v0;
                C[(size_t)row * N + ccol0 + 16] = v1;
            }
        }
    }
}

// ---------------- MFMA flash attention v2 (swapped QK^T, no scalar LDS writes) ----------------
// grid (17, H, B), block 256 = 4 waves. Wave wv owns q rows 16wv..16wv+15.
// S^T = mfma(K, Q): lane holds P^T[k=16c+4fq+rr][q=fr] -> lane-local softmax stats.
// PV a-frags assembled in-register via packed-quad shuffles. V pre-transposed in global.
__global__ __launch_bounds__(256) void attn_mfma_kernel(
    const float* __restrict__ Q, const float* __restrict__ Kb,
    const float* __restrict__ Vt, float* __restrict__ O) {
    constexpr int LDP = 72;     // 144B row stride -> conflict-free b128 frag reads
    __shared__ alignas(16) __bf16 Kh[64][LDP], Klo[64][LDP];
    __shared__ alignas(16) __bf16 Vh[64][LDP], Vlo[64][LDP];

    const int tid  = threadIdx.x;
    const int lane = tid & 63;
    const int wv   = tid >> 6;
    const int fr   = lane & 15;
    const int fq   = lane >> 4;
    const int fq8  = fq * 8;
    const int qt = blockIdx.x, h = blockIdx.y, b = blockIdx.z;
    const int q0 = qt * 64;
    const size_t base   = (size_t)b * L_ * D_ + h * DH_;
    const size_t vtbase = (size_t)(b * H_ + h) * DH_ * LP_;

    // ---- Q fragments (b-operand) direct from global, split hi/lo ----
    bf16x8 bqh[2], bql[2];
    {
        int gq = q0 + 16 * wv + fr; if (gq > L_ - 1) gq = L_ - 1;
        const float* qrow = Q + base + (size_t)gq * D_;
#pragma unroll
        for (int s = 0; s < 2; ++s) {
            float4 f0 = *(const float4*)&qrow[s * 32 + fq8];
            float4 f1 = *(const float4*)&qrow[s * 32 + fq8 + 4];
            U4 hh, ll;
            hh.u[0] = pk2f(f0.x, f0.y); hh.u[1] = pk2f(f0.z, f0.w);
            hh.u[2] = pk2f(f1.x, f1.y); hh.u[3] = pk2f(f1.z, f1.w);
            ll.u[0] = pk2f(bflo(f0.x), bflo(f0.y)); ll.u[1] = pk2f(bflo(f0.z), bflo(f0.w));
            ll.u[2] = pk2f(bflo(f1.x), bflo(f1.y)); ll.u[3] = pk2f(bflo(f1.z), bflo(f1.w));
            bqh[s] = hh.f; bql[s] = ll.f;
        }
    }

    float m = -1e30f, l = 0.f;
    f32x4 oA[4];
#pragma unroll
    for (int c = 0; c < 4; ++c) oA[c] = (f32x4){0.f, 0.f, 0.f, 0.f};

    for (int kt = 0; kt < L_; kt += 64) {
        __syncthreads();
        // ---- stage K rows + Vt rows (both k-contiguous, vectorized, conflict-free) ----
#pragma unroll
        for (int rep = 0; rep < 4; ++rep) {
            int f = tid + rep * 256;         // 0..1023
            int r = f >> 4, cq = f & 15;
            int gr = kt + r; if (gr > L_ - 1) gr = L_ - 1;
            float4 kv = *(const float4*)&Kb[base + (size_t)gr * D_ + cq * 4];
            bf16x4 hh, ll;
            bfpair p0 = split_bf(kv.x); hh[0] = p0.h; ll[0] = p0.l;
            bfpair p1 = split_bf(kv.y); hh[1] = p1.h; ll[1] = p1.l;
            bfpair p2 = split_bf(kv.z); hh[2] = p2.h; ll[2] = p2.l;
            bfpair p3 = split_bf(kv.w); hh[3] = p3.h; ll[3] = p3.l;
            *(bf16x4*)&Kh[r][cq * 4]  = hh;
            *(bf16x4*)&Klo[r][cq * 4] = ll;
            float4 vv = *(const float4*)&Vt[vtbase + (size_t)r * LP_ + kt + cq * 4];
            bfpair q0p = split_bf(vv.x); hh[0] = q0p.h; ll[0] = q0p.l;
            bfpair q1p = split_bf(vv.y); hh[1] = q1p.h; ll[1] = q1p.l;
            bfpair q2p = split_bf(vv.z); hh[2] = q2p.h; ll[2] = q2p.l;
            bfpair q3p = split_bf(vv.w); hh[3] = q3p.h; ll[3] = q3p.l;
            *(bf16x4*)&Vh[r][cq * 4]  = hh;
            *(bf16x4*)&Vlo[r][cq * 4] = ll;
        }
        __syncthreads();

        // ---- S^T slice: rows k = 16c+4fq+rr, col q = fr ----
        float p[4][4];
#pragma unroll
        for (int c = 0; c < 4; ++c) {
            int row = 16 * c + fr;
            bf16x8 ah0 = *(bf16x8*)&Kh[row][fq8];
            bf16x8 ah1 = *(bf16x8*)&Kh[row][32 + fq8];
            bf16x8 al0 = *(bf16x8*)&Klo[row][fq8];
            bf16x8 al1 = *(bf16x8*)&Klo[row][32 + fq8];
            f32x4 s = (f32x4){0.f, 0.f, 0.f, 0.f};
            s = __builtin_amdgcn_mfma_f32_16x16x32_bf16(ah0, bqh[0], s, 0, 0, 0);
            s = __builtin_amdgcn_mfma_f32_16x16x32_bf16(ah1, bqh[1], s, 0, 0, 0);
            s = __builtin_amdgcn_mfma_f32_16x16x32_bf16(ah0, bql[0], s, 0, 0, 0);
            s = __builtin_amdgcn_mfma_f32_16x16x32_bf16(ah1, bql[1], s, 0, 0, 0);
            s = __builtin_amdgcn_mfma_f32_16x16x32_bf16(al0, bqh[0], s, 0, 0, 0);
            s = __builtin_amdgcn_mfma_f32_16x16x32_bf16(al1, bqh[1], s, 0, 0, 0);
#pragma unroll
            for (int rr = 0; rr < 4; ++rr) {
                int k = kt + 16 * c + 4 * fq + rr;
                p[c][rr] = (k < L_) ? s[rr] * SCALE_ : -1e30f;
            }
        }

        // ---- lane-local online softmax for q = fr (stats replicated across fq) ----
        float t = p[0][0];
#pragma unroll
        for (int c = 0; c < 4; ++c)
#pragma unroll
            for (int rr = 0; rr < 4; ++rr) t = fmaxf(t, p[c][rr]);
        t = fmaxf(t, __shfl_xor(t, 16));
        t = fmaxf(t, __shfl_xor(t, 32));
        float mn = fmaxf(m, t);
        float sclq = __expf(m - mn);
        m = mn;
        float ls = 0.f;
#pragma unroll
        for (int c = 0; c < 4; ++c)
#pragma unroll
            for (int rr = 0; rr < 4; ++rr) {
                float e = __expf(p[c][rr] - m);
                p[c][rr] = e;
                ls += e;
            }
        ls += __shfl_xor(ls, 16);
        ls += __shfl_xor(ls, 32);
        l = l * sclq + ls;

        // rescale O (O rows are q = 4fq+rr -> fetch scl from lane 4fq+rr)
#pragma unroll
        for (int rr = 0; rr < 4; ++rr) {
            float sO = __shfl(sclq, 4 * fq + rr);
#pragma unroll
            for (int c2 = 0; c2 < 4; ++c2) oA[c2][rr] *= sO;
        }

        // ---- pack P^T quads (k-consecutive), hi/lo ----
        uint32_t pqh[4][2], pql[4][2];
#pragma unroll
        for (int c = 0; c < 4; ++c) {
            pqh[c][0] = pk2f(p[c][0], p[c][1]);
            pqh[c][1] = pk2f(p[c][2], p[c][3]);
            pql[c][0] = pk2f(bflo(p[c][0]), bflo(p[c][1]));
            pql[c][1] = pk2f(bflo(p[c][2]), bflo(p[c][3]));
        }

        // ---- assemble PV a-frags: lane (fr,fq) needs P[q=fr][k=32s+8fq..+7] ----
        const int src0 = fr + ((fq & 1) << 5);   // source fq = 2*(fq&1)
        const int src1 = src0 + 16;              // source fq = 2*(fq&1)+1
        const bool sel = (fq >> 1) != 0;
        bf16x8 pah[2], pal[2];
#pragma unroll
        for (int s = 0; s < 2; ++s) {
            const int c0 = 2 * s, c1 = 2 * s + 1;
            uint32_t A0 = (uint32_t)__shfl((int)pqh[c0][0], src0);
            uint32_t A1 = (uint32_t)__shfl((int)pqh[c0][1], src0);
            uint32_t A2 = (uint32_t)__shfl((int)pqh[c0][0], src1);
            uint32_t A3 = (uint32_t)__shfl((int)pqh[c0][1], src1);
            uint32_t B0 = (uint32_t)__shfl((int)pqh[c1][0], src0);
            uint32_t B1 = (uint32_t)__shfl((int)pqh[c1][1], src0);
            uint32_t B2 = (uint32_t)__shfl((int)pqh[c1][0], src1);
            uint32_t B3 = (uint32_t)__shfl((int)pqh[c1][1], src1);
            U4 uh;
            uh.u[0] = sel ? B0 : A0; uh.u[1] = sel ? B1 : A1;
            uh.u[2] = sel ? B2 : A2; uh.u[3] = sel ? B3 : A3;
            pah[s] = uh.f;
            uint32_t C0 = (uint32_t)__shfl((int)pql[c0][0], src0);
            uint32_t C1 = (uint32_t)__shfl((int)pql[c0][1], src0);
            uint32_t C2 = (uint32_t)__shfl((int)pql[c0][0], src1);
            uint32_t C3 = (uint32_t)__shfl((int)pql[c0][1], src1);
            uint32_t D0 = (uint32_t)__shfl((int)pql[c1][0], src0);
            uint32_t D1 = (uint32_t)__shfl((int)pql[c1][1], src0);
            uint32_t D2 = (uint32_t)__shfl((int)pql[c1][0], src1);
            uint32_t D3 = (uint32_t)__shfl((int)pql[c1][1], src1);
            U4 ul;
            ul.u[0] = sel ? D0 : C0; ul.u[1] = sel ? D1 : C1;
            ul.u[2] = sel ? D2 : C2; ul.u[3] = sel ? D3 : C3;
            pal[s] = ul.f;
        }

        // ---- O += P · V (3-pass split; V staged as Vt rows d, k-contiguous) ----
#pragma unroll
        for (int c2 = 0; c2 < 4; ++c2) {
            int row = 16 * c2 + fr;
            bf16x8 bh0 = *(bf16x8*)&Vh[row][fq8];
            bf16x8 bh1 = *(bf16x8*)&Vh[row][32 + fq8];
            bf16x8 bl0 = *(bf16x8*)&Vlo[row][fq8];
            bf16x8 bl1 = *(bf16x8*)&Vlo[row][32 + fq8];
            f32x4 o = oA[c2];
            o = __builtin_amdgcn_mfma_f32_16x16x32_bf16(pah[0], bh0, o, 0, 0, 0);
            o = __builtin_amdgcn_mfma_f32_16x16x32_bf16(pah[1], bh1, o, 0, 0, 0);
            o = __builtin_amdgcn_mfma_f32_16x16x32_bf16(pah[0], bl0, o, 0, 0, 0);
            o = __builtin_amdgcn_mfma_f32_16x16x32_bf16(pah[1], bl1, o, 0, 0, 0);
            o = __builtin_amdgcn_mfma_f32_16x16x32_bf16(pal[0], bh0, o, 0, 0, 0);
            o = __builtin_amdgcn_mfma_f32_16x16x32_bf16(pal[1], bh1, o, 0, 0, 0);
            oA[c2] = o;
        }
    }

    // ---- epilogue ----
#pragma unroll
    for (int rr = 0; rr < 4; ++rr) {
        float lO = __shfl(l, 4 * fq + rr);
        int row = q0 + 16 * wv + 4 * fq + rr;
        if (row < L_) {
            float inv = 1.f / lO;
#pragma unroll
            for (int c2 = 0; c2 < 4; ++c2)
                O[base + (size_t)row * D_ + 16 * c2 + fr] = oA[c2][rr] * inv;
        }
    }
}

// ---------------- fused residual add + LayerNorm ----------------
__global__ __launch_bounds__(256) void add_ln_kernel(
    const float* __restrict__ X, const float* __restrict__ Y,
    const float* __restrict__ g, const float* __restrict__ be,
    float* __restrict__ Out) {
    int wave = threadIdx.x >> 6;
    int lane = threadIdx.x & 63;
    int row = blockIdx.x * 4 + wave;
    if (row >= M_) return;
    size_t base = (size_t)row * D_;
    int c0 = lane * 4, c1 = 256 + lane * 4;
    float4 xa = *(const float4*)&X[base + c0];
    float4 xb = *(const float4*)&X[base + c1];
    float4 ya = *(const float4*)&Y[base + c0];
    float4 yb = *(const float4*)&Y[base + c1];
    float v[8] = {xa.x + ya.x, xa.y + ya.y, xa.z + ya.z, xa.w + ya.w,
                  xb.x + yb.x, xb.y + yb.y, xb.z + yb.z, xb.w + yb.w};
    float s = 0.f, s2 = 0.f;
#pragma unroll
    for (int i = 0; i < 8; ++i) { s += v[i]; s2 = fmaf(v[i], v[i], s2); }
#pragma unroll
    for (int off = 32; off > 0; off >>= 1) {
        s  += __shfl_xor(s, off);
        s2 += __shfl_xor(s2, off);
    }
    float mean = s * (1.f / D_);
    float var  = s2 * (1.f / D_) - mean * mean;
    float rstd = rsqrtf(var + EPS_);
    float4 ga = *(const float4*)&g[c0];
    float4 gb = *(const float4*)&g[c1];
    float4 ba = *(const float4*)&be[c0];
    float4 bb = *(const float4*)&be[c1];
    float4 oa, ob;
    oa.x = (v[0] - mean) * rstd * ga.x + ba.x;
    oa.y = (v[1] - mean) * rstd * ga.y + ba.y;
    oa.z = (v[2] - mean) * rstd * ga.z + ba.z;
    oa.w = (v[3] - mean) * rstd * ga.w + ba.w;
    ob.x = (v[4] - mean) * rstd * gb.x + bb.x;
    ob.y = (v[5] - mean) * rstd * gb.y + bb.y;
    ob.z = (v[6] - mean) * rstd * gb.z + bb.z;
    ob.w = (v[7] - mean) * rstd * gb.w + bb.w;
    *(float4*)&Out[base + c0] = oa;
    *(float4*)&Out[base + c1] = ob;
}

// ---------------- launch ----------------
extern "C" void kernel_launch(void* const* d_in, const int* in_sizes, int n_in,
                              void* d_out, int out_size, void* d_ws, size_t ws_size,
                              hipStream_t stream) {
    const float* embed1 = (const float*)d_in[0];
    const float* embed2 = (const float*)d_in[1];
    const float* cls    = (const float*)d_in[2];
    const float* Wq = (const float*)d_in[3];
    const float* bq = (const float*)d_in[4];
    const float* Wk = (const float*)d_in[5];
    const float* bk = (const float*)d_in[6];
    const float* Wv = (const float*)d_in[7];
    const float* bv = (const float*)d_in[8];
    const float* Wo = (const float*)d_in[9];
    const float* bo = (const float*)d_in[10];
    const float* ln1g = (const float*)d_in[11];
    const float* ln1b = (const float*)d_in[12];
    const float* W1 = (const float*)d_in[13];
    const float* b1 = (const float*)d_in[14];
    const float* W2 = (const float*)d_in[15];
    const float* b2 = (const float*)d_in[16];
    const float* ln2g = (const float*)d_in[17];
    const float* ln2b = (const float*)d_in[18];

    const size_t SZ = (size_t)M_ * D_;
    float* ws = (float*)d_ws;
    float* X  = ws;
    float* X2 = ws + SZ;
    float* Qb = ws + 2 * SZ;
    float* Kb = ws + 3 * SZ;
    float* Vb = ws + 4 * SZ;
    float* Tb = ws + 5 * SZ;
    float* Hb = ws + 6 * SZ;                 // [M, DFF] (FFN phase only)
    float* Vt = Hb;                          // Vt [B*H, DH, LP_] aliases Hb (attn phase only)

    write_cls_kernel<<<(B_ * D_) / 256, 256, 0, stream>>>(cls, X, X2);
    transpose_embed_kernel<<<dim3(L0_ / 32, D_ / 32, B_), dim3(32, 8), 0, stream>>>(embed1, X);
    transpose_embed_kernel<<<dim3(L0_ / 32, D_ / 32, B_), dim3(32, 8), 0, stream>>>(embed2, X2);

    const int GM = (M_ + 127) / 128;         // 65
    const int g512  = GM * (512 / 64);       // 520
    const int g2048 = GM * (2048 / 64);      // 2080

    for (int l = 0; l < NLAYER_; ++l) {
        const float* Wq_l = Wq + (size_t)l * D_ * D_;
        const float* Wk_l = Wk + (size_t)l * D_ * D_;
        const float* Wv_l = Wv + (size_t)l * D_ * D_;
        const float* Wo_l = Wo + (size_t)l * D_ * D_;
        const float* W1_l = W1 + (size_t)l * DFF_ * D_;
        const float* W2_l = W2 + (size_t)l * D_ * DFF_;

        gemm_mfma_kernel<false><<<g512, 256, 0, stream>>>(
            X, Wq_l, bq + l * D_, Qb, M_, D_, D_);
        gemm_mfma_kernel<false><<<g512, 256, 0, stream>>>(
            X2, Wk_l, bk + l * D_, Kb, M_, D_, D_);
        gemm_mfma_kernel<false><<<g512, 256, 0, stream>>>(
            X2, Wv_l, bv + l * D_, Vb, M_, D_, D_);

        transpose_v_kernel<<<dim3(LP_ / 32, DH_ / 32, B_ * H_), dim3(32, 8), 0, stream>>>(Vb, Vt);

        attn_mfma_kernel<<<dim3((L_ + 63) / 64, H_, B_), 256, 0, stream>>>(Qb, Kb, Vt, Tb);

        gemm_mfma_kernel<false><<<g512, 256, 0, stream>>>(
            Tb, Wo_l, bo + l * D_, Qb, M_, D_, D_);

        add_ln_kernel<<<(M_ + 3) / 4, 256, 0, stream>>>(
            X, Qb, ln1g + l * D_, ln1b + l * D_, X);

        gemm_mfma_kernel<true><<<g2048, 256, 0, stream>>>(
            X, W1_l, b1 + l * DFF_, Hb, M_, DFF_, D_);
        gemm_mfma_kernel<false><<<g512, 256, 0, stream>>>(
            Hb, W2_l, b2 + l * D_, Tb, M_, D_, DFF_);

        float* out_ptr = (l == NLAYER_ - 1) ? (float*)d_out : X;
        add_ln_kernel<<<(M_ + 3) / 4, 256, 0, stream>>>(
            X, Tb, ln2g + l * D_, ln2b + l * D_, out_ptr);
    }
}